// Round 3
// baseline (1801.353 us; speedup 1.0000x reference)
//
#include <hip/hip_runtime.h>
#include <hip/hip_bf16.h>
#include <math.h>

typedef __hip_bfloat16 bf16;

#define D_MODEL 1024
#define D_INNER 2048
#define NTOK    4096   // B*L
#define SEQ     2048
#define BSZ     2
#define DSTATE  16
#define DTRANK  64
#define NCH     16
#define CHLEN   128    // SEQ / NCH
#define NPAIR   4096   // BSZ * D_INNER

__device__ __forceinline__ float b2f(bf16 v) { return __bfloat162float(v); }
__device__ __forceinline__ bf16  f2b(float v) { return __float2bfloat16(v); }

// ---------------------------------------------------------------- LayerNorm
// fp32 in -> bf16 out. one block per token, 256 threads, 4 elems/thread
__global__ void k_layernorm(const float* __restrict__ x, const float* __restrict__ g,
                            const float* __restrict__ b, bf16* __restrict__ xn) {
    int t = blockIdx.x;
    int tid = threadIdx.x;
    const float* row = x + (size_t)t * D_MODEL;
    float v[4];
    float s = 0.f, q = 0.f;
#pragma unroll
    for (int i = 0; i < 4; ++i) {
        int idx = tid + i * 256;
        v[i] = row[idx];
        s += v[i]; q += v[i] * v[i];
    }
    __shared__ float sh_s[256], sh_q[256];
    sh_s[tid] = s; sh_q[tid] = q;
    __syncthreads();
    for (int o = 128; o > 0; o >>= 1) {
        if (tid < o) { sh_s[tid] += sh_s[tid + o]; sh_q[tid] += sh_q[tid + o]; }
        __syncthreads();
    }
    float mu  = sh_s[0] * (1.f / D_MODEL);
    float var = sh_q[0] * (1.f / D_MODEL) - mu * mu;
    float rs  = rsqrtf(var + 1e-5f);
#pragma unroll
    for (int i = 0; i < 4; ++i) {
        int idx = tid + i * 256;
        float o = (v[i] - mu) * rs * g[idx] + b[idx];
        xn[(size_t)t * D_MODEL + idx] = f2b(o);
    }
}

// ---------------------------------------------------------------- GEMM (NT)
// C[m,n] = sum_k A[m,k]*B[n,k]; A bf16 row-major, B fp32 row-major, fp32 acc
// mode 0: n <  D_INNER -> Cf[m*D_INNER+n] fp32        (xc half)
//         n >= D_INNER -> Cz[m*D_INNER+n-D_INNER] bf16 (z half)
// mode 1: Cout[m*N+n] = acc + res[m*N+n]  (fp32)
#define BM 64
#define BN 64
#define BK 16
__global__ void k_gemm(const bf16* __restrict__ A, const float* __restrict__ B,
                       int M, int N, int K, int mode,
                       float* __restrict__ Cf, bf16* __restrict__ Cz,
                       const float* __restrict__ res, float* __restrict__ Cout) {
    __shared__ float As[BK][BM + 4];
    __shared__ float Bs[BK][BN + 4];
    int tid = threadIdx.x;
    int m0 = blockIdx.y * BM;
    int n0 = blockIdx.x * BN;
    int lc = tid & 15;       // k within tile
    int lr = tid >> 4;       // 0..15
    int tx = tid & 15, ty = tid >> 4;
    float acc[4][4] = {};
    for (int k0 = 0; k0 < K; k0 += BK) {
#pragma unroll
        for (int i = 0; i < 4; ++i) {
            int m = lr + 16 * i;
            As[lc][m] = b2f(A[(size_t)(m0 + m) * K + k0 + lc]);
            Bs[lc][m] = B[(size_t)(n0 + m) * K + k0 + lc];
        }
        __syncthreads();
#pragma unroll
        for (int kk = 0; kk < BK; ++kk) {
            float4 a4 = *reinterpret_cast<const float4*>(&As[kk][ty * 4]);
            float4 b4 = *reinterpret_cast<const float4*>(&Bs[kk][tx * 4]);
            float a[4] = {a4.x, a4.y, a4.z, a4.w};
            float bb[4] = {b4.x, b4.y, b4.z, b4.w};
#pragma unroll
            for (int i = 0; i < 4; ++i)
#pragma unroll
                for (int j = 0; j < 4; ++j)
                    acc[i][j] += a[i] * bb[j];
        }
        __syncthreads();
    }
#pragma unroll
    for (int i = 0; i < 4; ++i) {
        int m = m0 + ty * 4 + i;
#pragma unroll
        for (int j = 0; j < 4; ++j) {
            int n = n0 + tx * 4 + j;
            float v = acc[i][j];
            if (mode == 0) {
                if (n < D_INNER) Cf[(size_t)m * D_INNER + n] = v;
                else             Cz[(size_t)m * D_INNER + (n - D_INNER)] = f2b(v);
            } else {
                Cout[(size_t)m * N + n] = v + res[(size_t)m * N + n];
            }
        }
    }
}

// ------------------------------------------------- causal depthwise conv + SiLU
__global__ void k_conv(const float* __restrict__ xc, const float* __restrict__ cw,
                       const float* __restrict__ cb, bf16* __restrict__ xcs) {
    size_t idx = (size_t)blockIdx.x * blockDim.x + threadIdx.x;
    int d = (int)(idx & (D_INNER - 1));
    int l = (int)((idx >> 11) & (SEQ - 1));
    float w0 = cw[d * 4 + 0], w1 = cw[d * 4 + 1];
    float w2 = cw[d * 4 + 2], w3 = cw[d * 4 + 3];
    const float* base = xc + idx;
    float acc = cb[d] + w3 * base[0];
    if (l >= 1) acc += w2 * base[-(int)D_INNER];
    if (l >= 2) acc += w1 * base[-2 * (int)D_INNER];
    if (l >= 3) acc += w0 * base[-3 * (int)D_INNER];
    xcs[idx] = f2b(acc / (1.f + expf(-acc)));   // silu
}

// ------------------------------------------------- x_dbl = xc_s @ x_proj_w^T
__global__ void k_xproj(const bf16* __restrict__ xcs, const float* __restrict__ w,
                        float* __restrict__ xdbl) {
    int t = blockIdx.x;
    int tid = threadIdx.x;
    __shared__ float row[D_INNER];
    for (int i = tid; i < D_INNER; i += 128) row[i] = b2f(xcs[(size_t)t * D_INNER + i]);
    __syncthreads();
    if (tid < 96) {
        const float* wr = w + (size_t)tid * D_INNER;
        float acc = 0.f;
        for (int d0 = 0; d0 < D_INNER; d0 += 8) {
#pragma unroll
            for (int u = 0; u < 8; ++u) acc += row[d0 + u] * wr[d0 + u];
        }
        xdbl[(size_t)t * 96 + tid] = acc;
    }
}

// ------------------------------------------------- delta = softplus(dr @ dt_w^T + dt_b)
__global__ void k_delta(const float* __restrict__ xdbl, const float* __restrict__ dtw,
                        const float* __restrict__ dtb, float* __restrict__ delta) {
    int t = blockIdx.x;
    int tid = threadIdx.x;
    __shared__ float r[DTRANK];
    if (tid < DTRANK) r[tid] = xdbl[(size_t)t * 96 + tid];
    __syncthreads();
    for (int d = tid; d < D_INNER; d += 256) {
        const float* wr = dtw + (size_t)d * DTRANK;
        float acc = dtb[d];
#pragma unroll
        for (int j = 0; j < DTRANK; ++j) acc += r[j] * wr[j];
        float dl = (acc > 20.f) ? acc : log1pf(expf(acc));
        delta[(size_t)t * D_INNER + d] = dl;
    }
}

// ------------------------------------------------- scan pass A: per-chunk partials
__global__ void k_scan_partial(const float* __restrict__ delta, const bf16* __restrict__ xcs,
                               const float* __restrict__ xdbl, const float* __restrict__ A_log,
                               float* __restrict__ cha, float* __restrict__ chs) {
    int tid = threadIdx.x;
    int g = blockIdx.x * 16 + (tid >> 4);
    int n = tid & 15;
    int pair = g & (NPAIR - 1);
    int chunk = g >> 12;
    int b = pair >> 11;
    int d = pair & (D_INNER - 1);
    float A = -expf(A_log[d * DSTATE + n]);
    float aprod = 1.f, s = 0.f;
    size_t tbase = (size_t)b * SEQ + chunk * CHLEN;
    for (int i = 0; i < CHLEN; ++i) {
        size_t t = tbase + i;
        float dl = delta[t * D_INNER + d];
        float u  = b2f(xcs[t * D_INNER + d]);
        float Bn = xdbl[t * 96 + 64 + n];
        float dA = expf(dl * A);
        s = dA * s + dl * Bn * u;
        aprod *= dA;
    }
    size_t o = ((size_t)pair * NCH + chunk) * DSTATE + n;
    cha[o] = aprod; chs[o] = s;
}

// ------------------------------------------------- scan pass B: chunk-prefix combine
// NOTE: sst aliases cha — read cha/chs BEFORE writing sst (same thread, same element)
__global__ void k_scan_combine(const float* __restrict__ cha, const float* __restrict__ chs,
                               float* __restrict__ sst) {
    int idx = blockIdx.x * 256 + threadIdx.x;
    int pair = idx >> 4;
    int n = idx & 15;
    float s = 0.f;
#pragma unroll
    for (int c = 0; c < NCH; ++c) {
        size_t o = ((size_t)pair * NCH + c) * DSTATE + n;
        float a = cha[o];
        float b = chs[o];
        sst[o] = s;
        s = a * s + b;
    }
}

// ------------------------------------------------- scan pass C: final y + gate
// NOTE: yf aliases zbuf elementwise — z[t,d] read then yf[t,d] written by the
// same lane in the same iteration; no other thread touches that element.
__global__ void k_scan_final(const float* __restrict__ delta, const bf16* __restrict__ xcs,
                             const float* __restrict__ xdbl, const bf16* __restrict__ zbuf,
                             const float* __restrict__ A_log, const float* __restrict__ Dp,
                             const float* __restrict__ sst, bf16* __restrict__ yf) {
    int tid = threadIdx.x;
    int g = blockIdx.x * 16 + (tid >> 4);
    int n = tid & 15;
    int pair = g & (NPAIR - 1);
    int chunk = g >> 12;
    int b = pair >> 11;
    int d = pair & (D_INNER - 1);
    float A  = -expf(A_log[d * DSTATE + n]);
    float Dv = Dp[d];
    float s  = sst[((size_t)pair * NCH + chunk) * DSTATE + n];
    size_t tbase = (size_t)b * SEQ + chunk * CHLEN;
    for (int i = 0; i < CHLEN; ++i) {
        size_t t = tbase + i;
        float dl = delta[t * D_INNER + d];
        float u  = b2f(xcs[t * D_INNER + d]);
        float Bn = xdbl[t * 96 + 64 + n];
        float Cn = xdbl[t * 96 + 80 + n];
        float dA = expf(dl * A);
        s = dA * s + dl * Bn * u;
        float y = s * Cn;
        y += __shfl_xor(y, 1, 16);
        y += __shfl_xor(y, 2, 16);
        y += __shfl_xor(y, 4, 16);
        y += __shfl_xor(y, 8, 16);
        if (n == 0) {
            float zv = b2f(zbuf[t * D_INNER + d]);
            float sz = zv / (1.f + expf(-zv));
            yf[t * D_INNER + d] = f2b((y + u * Dv) * sz);
        }
    }
}

// ---------------------------------------------------------------- launch
extern "C" void kernel_launch(void* const* d_in, const int* in_sizes, int n_in,
                              void* d_out, int out_size, void* d_ws, size_t ws_size,
                              hipStream_t stream) {
    // ALL reference dtypes are float32 (reference file) — inputs and output fp32.
    const float* x      = (const float*)d_in[0];
    const float* ln_g   = (const float*)d_in[1];
    const float* ln_b   = (const float*)d_in[2];
    const float* W_in   = (const float*)d_in[3];
    const float* conv_w = (const float*)d_in[4];
    const float* conv_b = (const float*)d_in[5];
    const float* A_log  = (const float*)d_in[6];
    const float* D_par  = (const float*)d_in[7];
    const float* xpw    = (const float*)d_in[8];
    const float* dtw    = (const float*)d_in[9];
    const float* dtb    = (const float*)d_in[10];
    const float* W_out  = (const float*)d_in[11];
    float* out = (float*)d_out;

    char* ws = (char*)d_ws;
    // workspace layout (77,070,336 bytes), stage-lifetime aliased:
    //  [0,        8388608)  xn bf16 (dead after GEMM1) -> cha 4MB@0, chs 4MB@4MB; sst=cha
    //  [8388608, 41943040)  xc fp32 (dead after conv)  -> delta fp32
    //  [41943040,58720256)  z bf16                     <- yf aliases z (elementwise-safe)
    //  [58720256,75497472)  xcs bf16
    //  [75497472,77070336)  xdbl fp32 (4096x96)
    bf16*  xn    = (bf16*)(ws + 0);
    float* cha   = (float*)(ws + 0);
    float* chs   = (float*)(ws + 4194304);
    float* sst   = cha;
    float* xc    = (float*)(ws + 8388608);
    float* delta = xc;
    bf16*  z     = (bf16*)(ws + 41943040);
    bf16*  yf    = z;
    bf16*  xcs   = (bf16*)(ws + 58720256);
    float* xdbl  = (float*)(ws + 75497472);

    k_layernorm<<<NTOK, 256, 0, stream>>>(x, ln_g, ln_b, xn);
    k_gemm<<<dim3(2 * D_INNER / BN, NTOK / BM), 256, 0, stream>>>(
        xn, W_in, NTOK, 2 * D_INNER, D_MODEL, 0, xc, z, nullptr, nullptr);
    k_conv<<<(NTOK * D_INNER) / 256, 256, 0, stream>>>(xc, conv_w, conv_b, xcs);
    k_xproj<<<NTOK, 128, 0, stream>>>(xcs, xpw, xdbl);
    k_delta<<<NTOK, 256, 0, stream>>>(xdbl, dtw, dtb, delta);
    k_scan_partial<<<(NPAIR * NCH) / 16, 256, 0, stream>>>(delta, xcs, xdbl, A_log, cha, chs);
    k_scan_combine<<<(NPAIR * DSTATE) / 256, 256, 0, stream>>>(cha, chs, sst);
    k_scan_final<<<(NPAIR * NCH) / 16, 256, 0, stream>>>(delta, xcs, xdbl, z, A_log, D_par, sst, yf);
    k_gemm<<<dim3(D_MODEL / BN, NTOK / BM), 256, 0, stream>>>(
        yf, W_out, NTOK, D_MODEL, D_INNER, 1, nullptr, nullptr, x, out);
}

// Round 4
// 1256.189 us; speedup vs baseline: 1.4340x; 1.4340x over previous
//
#include <hip/hip_runtime.h>
#include <hip/hip_bf16.h>
#include <math.h>

typedef __hip_bfloat16 bf16;

#define D_MODEL 1024
#define D_INNER 2048
#define NTOK    4096   // B*L
#define SEQ     2048
#define BSZ     2
#define DSTATE  16
#define DTRANK  64
#define NCH     16
#define CHLEN   128    // SEQ / NCH
#define NPAIR   4096   // BSZ * D_INNER

__device__ __forceinline__ float b2f(bf16 v) { return __bfloat162float(v); }
__device__ __forceinline__ bf16  f2b(float v) { return __float2bfloat16(v); }
__device__ __forceinline__ short f2bs(float v) {
    bf16 h = __float2bfloat16(v);
    short s; __builtin_memcpy(&s, &h, 2); return s;
}

typedef __attribute__((ext_vector_type(8))) short short8;
typedef __attribute__((ext_vector_type(4))) float f32x4;

// async global->LDS, 16B per lane; LDS dest is wave-uniform base + lane*16
__device__ __forceinline__ void async_copy16(const void* g, void* l) {
    __builtin_amdgcn_global_load_lds(
        (const __attribute__((address_space(1))) unsigned int*)g,
        (__attribute__((address_space(3))) unsigned int*)l,
        16, 0, 0);
}

// ---------------------------------------------------------------- LayerNorm
__global__ void k_layernorm(const float* __restrict__ x, const float* __restrict__ g,
                            const float* __restrict__ b, bf16* __restrict__ xn) {
    int t = blockIdx.x;
    int tid = threadIdx.x;
    const float* row = x + (size_t)t * D_MODEL;
    float v[4];
    float s = 0.f, q = 0.f;
#pragma unroll
    for (int i = 0; i < 4; ++i) {
        int idx = tid + i * 256;
        v[i] = row[idx];
        s += v[i]; q += v[i] * v[i];
    }
    __shared__ float sh_s[256], sh_q[256];
    sh_s[tid] = s; sh_q[tid] = q;
    __syncthreads();
    for (int o = 128; o > 0; o >>= 1) {
        if (tid < o) { sh_s[tid] += sh_s[tid + o]; sh_q[tid] += sh_q[tid + o]; }
        __syncthreads();
    }
    float mu  = sh_s[0] * (1.f / D_MODEL);
    float var = sh_q[0] * (1.f / D_MODEL) - mu * mu;
    float rs  = rsqrtf(var + 1e-5f);
#pragma unroll
    for (int i = 0; i < 4; ++i) {
        int idx = tid + i * 256;
        float o = (v[i] - mu) * rs * g[idx] + b[idx];
        xn[(size_t)t * D_MODEL + idx] = f2b(o);
    }
}

// ---------------------------------------------------------------- fp32 -> bf16 convert
__global__ void k_f2b(const float* __restrict__ in, short* __restrict__ out) {
    int i = blockIdx.x * 256 + threadIdx.x;   // one float4 per thread
    float4 v = reinterpret_cast<const float4*>(in)[i];
    short4 o;
    o.x = f2bs(v.x); o.y = f2bs(v.y); o.z = f2bs(v.z); o.w = f2bs(v.w);
    reinterpret_cast<short4*>(out)[i] = o;
}

// ---------------------------------------------------------------- MFMA GEMM (NT)
// C[m,n] = sum_k A[m,k]*B[n,k]; A,B bf16(short) row-major K-contiguous.
// 128x128 block tile, BK=32, 4 waves each computing 64x64 via 4x4 of 16x16x32.
// mode 0: n < D_INNER -> Cf fp32 ; else -> Cz bf16   (in-proj split)
// mode 1: Cout[m*N+n] = acc + res[m*N+n] (fp32, residual add)
#define GBK 32
__global__ __launch_bounds__(256) void k_gemm_mfma(
    const short* __restrict__ A, const short* __restrict__ Bw,
    int N, int K, int mode,
    float* __restrict__ Cf, bf16* __restrict__ Cz,
    const float* __restrict__ res, float* __restrict__ Cout)
{
    __shared__ short As[128 * GBK];   // 8 KB, [row][k] row-major, NO padding (global_load_lds order)
    __shared__ short Bs[128 * GBK];   // 8 KB
    const int tid  = threadIdx.x;
    const int lane = tid & 63;
    const int wave = tid >> 6;
    const int wm = wave >> 1, wn = wave & 1;
    const int m0 = blockIdx.y * 128;
    const int n0 = blockIdx.x * 128;
    const int lm   = lane & 15;
    const int koff = (lane >> 4) * 8;

    // staging: thread tid stages 16B chunks; round r covers rows r*64..r*64+63
    const int srow = tid >> 2;            // 0..63
    const int skc  = (tid & 3) * 8;       // k element offset
    const size_t a_off0 = (size_t)(m0 + srow) * K + skc;
    const size_t a_off1 = (size_t)(m0 + srow + 64) * K + skc;
    const size_t b_off0 = (size_t)(n0 + srow) * K + skc;
    const size_t b_off1 = (size_t)(n0 + srow + 64) * K + skc;
    char* lA0 = (char*)As + tid * 16;
    char* lA1 = (char*)As + 4096 + tid * 16;
    char* lB0 = (char*)Bs + tid * 16;
    char* lB1 = (char*)Bs + 4096 + tid * 16;

    f32x4 acc[4][4];
#pragma unroll
    for (int i = 0; i < 4; ++i)
#pragma unroll
        for (int j = 0; j < 4; ++j)
            acc[i][j] = (f32x4){0.f, 0.f, 0.f, 0.f};

    for (int k0 = 0; k0 < K; k0 += GBK) {
        __syncthreads();                       // previous compute done before overwrite
        async_copy16(A + a_off0 + k0, lA0);
        async_copy16(A + a_off1 + k0, lA1);
        async_copy16(Bw + b_off0 + k0, lB0);
        async_copy16(Bw + b_off1 + k0, lB1);
        __syncthreads();                       // drains vmcnt before barrier

        short8 af[4], bf[4];
#pragma unroll
        for (int t = 0; t < 4; ++t) {
            af[t] = *reinterpret_cast<const short8*>(&As[(wm * 64 + t * 16 + lm) * GBK + koff]);
            bf[t] = *reinterpret_cast<const short8*>(&Bs[(wn * 64 + t * 16 + lm) * GBK + koff]);
        }
#pragma unroll
        for (int tm = 0; tm < 4; ++tm)
#pragma unroll
            for (int tn = 0; tn < 4; ++tn)
                acc[tm][tn] = __builtin_amdgcn_mfma_f32_16x16x32_bf16(
                    af[tm], bf[tn], acc[tm][tn], 0, 0, 0);
    }

    // epilogue: C row = quad*4+reg, col = lane&15 (m89-verified layout)
    const int rq = (lane >> 4) * 4;
#pragma unroll
    for (int tm = 0; tm < 4; ++tm) {
#pragma unroll
        for (int tn = 0; tn < 4; ++tn) {
            f32x4 v = acc[tm][tn];
            int col = n0 + wn * 64 + tn * 16 + lm;
#pragma unroll
            for (int r = 0; r < 4; ++r) {
                int row = m0 + wm * 64 + tm * 16 + rq + r;
                float val = v[r];
                if (mode == 0) {
                    if (col < D_INNER) Cf[(size_t)row * D_INNER + col] = val;
                    else               Cz[(size_t)row * D_INNER + (col - D_INNER)] = f2b(val);
                } else {
                    Cout[(size_t)row * N + col] = val + res[(size_t)row * N + col];
                }
            }
        }
    }
}

// ------------------------------------------------- causal depthwise conv + SiLU
__global__ void k_conv(const float* __restrict__ xc, const float* __restrict__ cw,
                       const float* __restrict__ cb, bf16* __restrict__ xcs) {
    size_t idx = (size_t)blockIdx.x * blockDim.x + threadIdx.x;
    int d = (int)(idx & (D_INNER - 1));
    int l = (int)((idx >> 11) & (SEQ - 1));
    float w0 = cw[d * 4 + 0], w1 = cw[d * 4 + 1];
    float w2 = cw[d * 4 + 2], w3 = cw[d * 4 + 3];
    const float* base = xc + idx;
    float acc = cb[d] + w3 * base[0];
    if (l >= 1) acc += w2 * base[-(int)D_INNER];
    if (l >= 2) acc += w1 * base[-2 * (int)D_INNER];
    if (l >= 3) acc += w0 * base[-3 * (int)D_INNER];
    xcs[idx] = f2b(acc / (1.f + expf(-acc)));   // silu
}

// ------------------------------------------------- x_dbl = xc_s @ x_proj_w^T
__global__ void k_xproj(const bf16* __restrict__ xcs, const float* __restrict__ w,
                        float* __restrict__ xdbl) {
    int t = blockIdx.x;
    int tid = threadIdx.x;
    __shared__ float row[D_INNER];
    for (int i = tid; i < D_INNER; i += 128) row[i] = b2f(xcs[(size_t)t * D_INNER + i]);
    __syncthreads();
    if (tid < 96) {
        const float* wr = w + (size_t)tid * D_INNER;
        float acc = 0.f;
        for (int d0 = 0; d0 < D_INNER; d0 += 8) {
#pragma unroll
            for (int u = 0; u < 8; ++u) acc += row[d0 + u] * wr[d0 + u];
        }
        xdbl[(size_t)t * 96 + tid] = acc;
    }
}

// ------------------------------------------------- delta = softplus(dr @ dt_w^T + dt_b)
__global__ void k_delta(const float* __restrict__ xdbl, const float* __restrict__ dtw,
                        const float* __restrict__ dtb, float* __restrict__ delta) {
    int t = blockIdx.x;
    int tid = threadIdx.x;
    __shared__ float r[DTRANK];
    if (tid < DTRANK) r[tid] = xdbl[(size_t)t * 96 + tid];
    __syncthreads();
    for (int d = tid; d < D_INNER; d += 256) {
        const float* wr = dtw + (size_t)d * DTRANK;
        float acc = dtb[d];
#pragma unroll
        for (int j = 0; j < DTRANK; ++j) acc += r[j] * wr[j];
        float dl = (acc > 20.f) ? acc : log1pf(expf(acc));
        delta[(size_t)t * D_INNER + d] = dl;
    }
}

// ------------------------------------------------- scan pass A: per-chunk partials
__global__ void k_scan_partial(const float* __restrict__ delta, const bf16* __restrict__ xcs,
                               const float* __restrict__ xdbl, const float* __restrict__ A_log,
                               float* __restrict__ cha, float* __restrict__ chs) {
    int tid = threadIdx.x;
    int g = blockIdx.x * 16 + (tid >> 4);
    int n = tid & 15;
    int pair = g & (NPAIR - 1);
    int chunk = g >> 12;
    int b = pair >> 11;
    int d = pair & (D_INNER - 1);
    float A = -expf(A_log[d * DSTATE + n]);
    float aprod = 1.f, s = 0.f;
    size_t tbase = (size_t)b * SEQ + chunk * CHLEN;
    for (int i = 0; i < CHLEN; ++i) {
        size_t t = tbase + i;
        float dl = delta[t * D_INNER + d];
        float u  = b2f(xcs[t * D_INNER + d]);
        float Bn = xdbl[t * 96 + 64 + n];
        float dA = expf(dl * A);
        s = dA * s + dl * Bn * u;
        aprod *= dA;
    }
    size_t o = ((size_t)pair * NCH + chunk) * DSTATE + n;
    cha[o] = aprod; chs[o] = s;
}

// ------------------------------------------------- scan pass B: chunk-prefix combine
// NOTE: sst aliases cha — read cha/chs BEFORE writing sst (same thread, same element)
__global__ void k_scan_combine(const float* __restrict__ cha, const float* __restrict__ chs,
                               float* __restrict__ sst) {
    int idx = blockIdx.x * 256 + threadIdx.x;
    int pair = idx >> 4;
    int n = idx & 15;
    float s = 0.f;
#pragma unroll
    for (int c = 0; c < NCH; ++c) {
        size_t o = ((size_t)pair * NCH + c) * DSTATE + n;
        float a = cha[o];
        float b = chs[o];
        sst[o] = s;
        s = a * s + b;
    }
}

// ------------------------------------------------- scan pass C: final y + gate
// NOTE: yf aliases zbuf elementwise — same-lane read-then-write, safe.
__global__ void k_scan_final(const float* __restrict__ delta, const bf16* __restrict__ xcs,
                             const float* __restrict__ xdbl, const bf16* __restrict__ zbuf,
                             const float* __restrict__ A_log, const float* __restrict__ Dp,
                             const float* __restrict__ sst, bf16* __restrict__ yf) {
    int tid = threadIdx.x;
    int g = blockIdx.x * 16 + (tid >> 4);
    int n = tid & 15;
    int pair = g & (NPAIR - 1);
    int chunk = g >> 12;
    int b = pair >> 11;
    int d = pair & (D_INNER - 1);
    float A  = -expf(A_log[d * DSTATE + n]);
    float Dv = Dp[d];
    float s  = sst[((size_t)pair * NCH + chunk) * DSTATE + n];
    size_t tbase = (size_t)b * SEQ + chunk * CHLEN;
    for (int i = 0; i < CHLEN; ++i) {
        size_t t = tbase + i;
        float dl = delta[t * D_INNER + d];
        float u  = b2f(xcs[t * D_INNER + d]);
        float Bn = xdbl[t * 96 + 64 + n];
        float Cn = xdbl[t * 96 + 80 + n];
        float dA = expf(dl * A);
        s = dA * s + dl * Bn * u;
        float y = s * Cn;
        y += __shfl_xor(y, 1, 16);
        y += __shfl_xor(y, 2, 16);
        y += __shfl_xor(y, 4, 16);
        y += __shfl_xor(y, 8, 16);
        if (n == 0) {
            float zv = b2f(zbuf[t * D_INNER + d]);
            float sz = zv / (1.f + expf(-zv));
            yf[t * D_INNER + d] = f2b((y + u * Dv) * sz);
        }
    }
}

// ---------------------------------------------------------------- launch
extern "C" void kernel_launch(void* const* d_in, const int* in_sizes, int n_in,
                              void* d_out, int out_size, void* d_ws, size_t ws_size,
                              hipStream_t stream) {
    const float* x      = (const float*)d_in[0];
    const float* ln_g   = (const float*)d_in[1];
    const float* ln_b   = (const float*)d_in[2];
    const float* W_in   = (const float*)d_in[3];
    const float* conv_w = (const float*)d_in[4];
    const float* conv_b = (const float*)d_in[5];
    const float* A_log  = (const float*)d_in[6];
    const float* D_par  = (const float*)d_in[7];
    const float* xpw    = (const float*)d_in[8];
    const float* dtw    = (const float*)d_in[9];
    const float* dtb    = (const float*)d_in[10];
    const float* W_out  = (const float*)d_in[11];
    float* out = (float*)d_out;

    char* ws = (char*)d_ws;
    // workspace (77,070,336 B), stage-lifetime aliased:
    //  [0,        8388608)  xn bf16 (dead after GEMM1) -> cha 4MB@0, chs 4MB@4MB; sst=cha
    //  [8388608, 41943040)  xc fp32 (dead after conv)  -> delta fp32 -> wOutb bf16 (after scan_final)
    //  [41943040,58720256)  z bf16                     <- yf aliases z (elementwise-safe)
    //  [58720256,75497472)  wInb bf16 (dead after GEMM1) -> xcs bf16
    //  [75497472,77070336)  xdbl fp32 (4096x96)
    bf16*  xn    = (bf16*)(ws + 0);
    float* cha   = (float*)(ws + 0);
    float* chs   = (float*)(ws + 4194304);
    float* sst   = cha;
    float* xc    = (float*)(ws + 8388608);
    float* delta = xc;
    short* wOutb = (short*)(ws + 8388608);     // after delta is dead
    bf16*  z     = (bf16*)(ws + 41943040);
    bf16*  yf    = z;
    short* wInb  = (short*)(ws + 58720256);    // before xcs exists
    bf16*  xcs   = (bf16*)(ws + 58720256);
    float* xdbl  = (float*)(ws + 75497472);

    k_layernorm<<<NTOK, 256, 0, stream>>>(x, ln_g, ln_b, xn);
    k_f2b<<<(2 * D_INNER * D_MODEL / 4) / 256, 256, 0, stream>>>(W_in, wInb);
    k_gemm_mfma<<<dim3(2 * D_INNER / 128, NTOK / 128), 256, 0, stream>>>(
        (const short*)xn, wInb, 2 * D_INNER, D_MODEL, 0, xc, z, nullptr, nullptr);
    k_conv<<<(NTOK * D_INNER) / 256, 256, 0, stream>>>(xc, conv_w, conv_b, xcs);
    k_xproj<<<NTOK, 128, 0, stream>>>(xcs, xpw, xdbl);
    k_delta<<<NTOK, 256, 0, stream>>>(xdbl, dtw, dtb, delta);
    k_scan_partial<<<(NPAIR * NCH) / 16, 256, 0, stream>>>(delta, xcs, xdbl, A_log, cha, chs);
    k_scan_combine<<<(NPAIR * DSTATE) / 256, 256, 0, stream>>>(cha, chs, sst);
    k_scan_final<<<(NPAIR * NCH) / 16, 256, 0, stream>>>(delta, xcs, xdbl, z, A_log, D_par, sst, yf);
    k_f2b<<<(D_MODEL * D_INNER / 4) / 256, 256, 0, stream>>>(W_out, wOutb);
    k_gemm_mfma<<<dim3(D_MODEL / 128, NTOK / 128), 256, 0, stream>>>(
        (const short*)yf, wOutb, D_MODEL, D_INNER, 1, nullptr, nullptr, x, out);
}

// Round 5
// 682.947 us; speedup vs baseline: 2.6376x; 1.8394x over previous
//
#include <hip/hip_runtime.h>
#include <hip/hip_bf16.h>
#include <math.h>

typedef __hip_bfloat16 bf16;

#define D_MODEL 1024
#define D_INNER 2048
#define NTOK    4096   // B*L
#define SEQ     2048
#define BSZ     2
#define DSTATE  16
#define DTRANK  64
#define NCH     16
#define CHLEN   128    // SEQ / NCH
#define NPAIR   4096   // BSZ * D_INNER
#define XDS     128    // xdbl row stride (fp32), padded from 96

__device__ __forceinline__ float b2f(bf16 v) { return __bfloat162float(v); }
__device__ __forceinline__ bf16  f2b(float v) { return __float2bfloat16(v); }
__device__ __forceinline__ short f2bs(float v) {
    bf16 h = __float2bfloat16(v);
    short s; __builtin_memcpy(&s, &h, 2); return s;
}

typedef __attribute__((ext_vector_type(8))) short short8;
typedef __attribute__((ext_vector_type(4))) float f32x4;

__device__ __forceinline__ void async_copy16(const void* g, void* l) {
    __builtin_amdgcn_global_load_lds(
        (const __attribute__((address_space(1))) unsigned int*)g,
        (__attribute__((address_space(3))) unsigned int*)l,
        16, 0, 0);
}

// ---------------------------------------------------------------- LayerNorm
__global__ void k_layernorm(const float* __restrict__ x, const float* __restrict__ g,
                            const float* __restrict__ b, bf16* __restrict__ xn) {
    int t = blockIdx.x;
    int tid = threadIdx.x;
    const float* row = x + (size_t)t * D_MODEL;
    float v[4];
    float s = 0.f, q = 0.f;
#pragma unroll
    for (int i = 0; i < 4; ++i) {
        int idx = tid + i * 256;
        v[i] = row[idx];
        s += v[i]; q += v[i] * v[i];
    }
    __shared__ float sh_s[256], sh_q[256];
    sh_s[tid] = s; sh_q[tid] = q;
    __syncthreads();
    for (int o = 128; o > 0; o >>= 1) {
        if (tid < o) { sh_s[tid] += sh_s[tid + o]; sh_q[tid] += sh_q[tid + o]; }
        __syncthreads();
    }
    float mu  = sh_s[0] * (1.f / D_MODEL);
    float var = sh_q[0] * (1.f / D_MODEL) - mu * mu;
    float rs  = rsqrtf(var + 1e-5f);
#pragma unroll
    for (int i = 0; i < 4; ++i) {
        int idx = tid + i * 256;
        float o = (v[i] - mu) * rs * g[idx] + b[idx];
        xn[(size_t)t * D_MODEL + idx] = f2b(o);
    }
}

// ---------------------------------------------------------------- fp32 -> bf16 convert
__global__ void k_f2b(const float* __restrict__ in, short* __restrict__ out) {
    int i = blockIdx.x * 256 + threadIdx.x;
    float4 v = reinterpret_cast<const float4*>(in)[i];
    short4 o;
    o.x = f2bs(v.x); o.y = f2bs(v.y); o.z = f2bs(v.z); o.w = f2bs(v.w);
    reinterpret_cast<short4*>(out)[i] = o;
}

// ---------------------------------------------------------------- zero fp32 buffer
__global__ void k_zero(float* __restrict__ p) {
    int i = blockIdx.x * 256 + threadIdx.x;
    reinterpret_cast<float4*>(p)[i] = (float4){0.f, 0.f, 0.f, 0.f};
}

// --------------------------------------------- xpw (96x2048 fp32) -> padded 128x2048 bf16
__global__ void k_prep_xpw(const float* __restrict__ in, short* __restrict__ out) {
    int i = blockIdx.x * 256 + threadIdx.x;       // i over 128*2048/4
    int row = i >> 9;                              // /512 (512 float4 per row)
    short4 o;
    if (row < 96) {
        float4 v = reinterpret_cast<const float4*>(in)[i];
        o.x = f2bs(v.x); o.y = f2bs(v.y); o.z = f2bs(v.z); o.w = f2bs(v.w);
    } else {
        o.x = o.y = o.z = o.w = 0;
    }
    reinterpret_cast<short4*>(out)[i] = o;
}

// --------------------------------------------- dr = xdbl[:, 0:64] -> bf16 (4096x64)
__global__ void k_extract_dr(const float* __restrict__ xdbl, short* __restrict__ drb) {
    int i = blockIdx.x * 256 + threadIdx.x;       // i over 4096*16
    int t = i >> 4;
    int jg = (i & 15) * 4;
    float4 v = *reinterpret_cast<const float4*>(&xdbl[(size_t)t * XDS + jg]);
    short4 o;
    o.x = f2bs(v.x); o.y = f2bs(v.y); o.z = f2bs(v.z); o.w = f2bs(v.w);
    *reinterpret_cast<short4*>(&drb[(size_t)t * DTRANK + jg]) = o;
}

// ---------------------------------------------------------------- MFMA GEMM (NT)
// C[m,n] = sum_k A[m,k]*B[n,k]; A,B bf16(short) row-major K-contiguous.
// 128x128 tile, BK=32, 4 waves x (4x4) 16x16x32 MFMA.
// mode 0: split at D_INNER -> Cf fp32 / Cz bf16   (in-proj)
// mode 1: Cout = acc + res (fp32, residual)      (out-proj)
// mode 2: atomicAdd(Cf, acc)                      (xproj, split-K via blockIdx.z)
// mode 3: Cf = softplus(acc + bias[col])          (delta)
#define GBK 32
__global__ __launch_bounds__(256) void k_gemm_mfma(
    const short* __restrict__ A, const short* __restrict__ Bw,
    int N, int K, int mode,
    float* __restrict__ Cf, bf16* __restrict__ Cz,
    const float* __restrict__ res, float* __restrict__ Cout,
    const float* __restrict__ bias)
{
    __shared__ short As[128 * GBK];
    __shared__ short Bs[128 * GBK];
    const int tid  = threadIdx.x;
    const int lane = tid & 63;
    const int wave = tid >> 6;
    const int wm = wave >> 1, wn = wave & 1;
    const int m0 = blockIdx.y * 128;
    const int n0 = blockIdx.x * 128;
    const int lm   = lane & 15;
    const int koff = (lane >> 4) * 8;

    const int srow = tid >> 2;
    const int skc  = (tid & 3) * 8;
    const size_t a_off0 = (size_t)(m0 + srow) * K + skc;
    const size_t a_off1 = (size_t)(m0 + srow + 64) * K + skc;
    const size_t b_off0 = (size_t)(n0 + srow) * K + skc;
    const size_t b_off1 = (size_t)(n0 + srow + 64) * K + skc;
    char* lA0 = (char*)As + tid * 16;
    char* lA1 = (char*)As + 4096 + tid * 16;
    char* lB0 = (char*)Bs + tid * 16;
    char* lB1 = (char*)Bs + 4096 + tid * 16;

    f32x4 acc[4][4];
#pragma unroll
    for (int i = 0; i < 4; ++i)
#pragma unroll
        for (int j = 0; j < 4; ++j)
            acc[i][j] = (f32x4){0.f, 0.f, 0.f, 0.f};

    const int kchunk = K / gridDim.z;
    const int kbeg = blockIdx.z * kchunk;
    const int kend = kbeg + kchunk;
    for (int k0 = kbeg; k0 < kend; k0 += GBK) {
        __syncthreads();
        async_copy16(A + a_off0 + k0, lA0);
        async_copy16(A + a_off1 + k0, lA1);
        async_copy16(Bw + b_off0 + k0, lB0);
        async_copy16(Bw + b_off1 + k0, lB1);
        __syncthreads();

        short8 af[4], bf[4];
#pragma unroll
        for (int t = 0; t < 4; ++t) {
            af[t] = *reinterpret_cast<const short8*>(&As[(wm * 64 + t * 16 + lm) * GBK + koff]);
            bf[t] = *reinterpret_cast<const short8*>(&Bs[(wn * 64 + t * 16 + lm) * GBK + koff]);
        }
#pragma unroll
        for (int tm = 0; tm < 4; ++tm)
#pragma unroll
            for (int tn = 0; tn < 4; ++tn)
                acc[tm][tn] = __builtin_amdgcn_mfma_f32_16x16x32_bf16(
                    af[tm], bf[tn], acc[tm][tn], 0, 0, 0);
    }

    const int rq = (lane >> 4) * 4;
#pragma unroll
    for (int tm = 0; tm < 4; ++tm) {
#pragma unroll
        for (int tn = 0; tn < 4; ++tn) {
            f32x4 v = acc[tm][tn];
            int col = n0 + wn * 64 + tn * 16 + lm;
#pragma unroll
            for (int r = 0; r < 4; ++r) {
                int row = m0 + wm * 64 + tm * 16 + rq + r;
                float val = v[r];
                if (mode == 0) {
                    if (col < D_INNER) Cf[(size_t)row * D_INNER + col] = val;
                    else               Cz[(size_t)row * D_INNER + (col - D_INNER)] = f2b(val);
                } else if (mode == 1) {
                    Cout[(size_t)row * N + col] = val + res[(size_t)row * N + col];
                } else if (mode == 2) {
                    atomicAdd(&Cf[(size_t)row * N + col], val);
                } else {
                    float a = val + bias[col];
                    float sp = (a > 20.f) ? a : log1pf(expf(a));
                    Cf[(size_t)row * N + col] = sp;
                }
            }
        }
    }
}

// ------------------------------------------------- causal depthwise conv + SiLU
__global__ void k_conv(const float* __restrict__ xc, const float* __restrict__ cw,
                       const float* __restrict__ cb, bf16* __restrict__ xcs) {
    size_t idx = (size_t)blockIdx.x * blockDim.x + threadIdx.x;
    int d = (int)(idx & (D_INNER - 1));
    int l = (int)((idx >> 11) & (SEQ - 1));
    float w0 = cw[d * 4 + 0], w1 = cw[d * 4 + 1];
    float w2 = cw[d * 4 + 2], w3 = cw[d * 4 + 3];
    const float* base = xc + idx;
    float acc = cb[d] + w3 * base[0];
    if (l >= 1) acc += w2 * base[-(int)D_INNER];
    if (l >= 2) acc += w1 * base[-2 * (int)D_INNER];
    if (l >= 3) acc += w0 * base[-3 * (int)D_INNER];
    xcs[idx] = f2b(acc / (1.f + expf(-acc)));   // silu
}

// ------------------------------------------------- scan pass A: per-chunk partials
__global__ void k_scan_partial(const float* __restrict__ delta, const bf16* __restrict__ xcs,
                               const float* __restrict__ xdbl, const float* __restrict__ A_log,
                               float* __restrict__ cha, float* __restrict__ chs) {
    int tid = threadIdx.x;
    int g = blockIdx.x * 16 + (tid >> 4);
    int n = tid & 15;
    int pair = g & (NPAIR - 1);
    int chunk = g >> 12;
    int b = pair >> 11;
    int d = pair & (D_INNER - 1);
    float A = -expf(A_log[d * DSTATE + n]);
    float aprod = 1.f, s = 0.f;
    size_t tbase = (size_t)b * SEQ + chunk * CHLEN;
    for (int i = 0; i < CHLEN; ++i) {
        size_t t = tbase + i;
        float dl = delta[t * D_INNER + d];
        float u  = b2f(xcs[t * D_INNER + d]);
        float Bn = xdbl[t * XDS + 64 + n];
        float dA = expf(dl * A);
        s = dA * s + dl * Bn * u;
        aprod *= dA;
    }
    size_t o = ((size_t)pair * NCH + chunk) * DSTATE + n;
    cha[o] = aprod; chs[o] = s;
}

// ------------------------------------------------- scan pass B: chunk-prefix combine
// NOTE: sst aliases cha — read cha/chs BEFORE writing sst (same thread, same element)
__global__ void k_scan_combine(const float* __restrict__ cha, const float* __restrict__ chs,
                               float* __restrict__ sst) {
    int idx = blockIdx.x * 256 + threadIdx.x;
    int pair = idx >> 4;
    int n = idx & 15;
    float s = 0.f;
#pragma unroll
    for (int c = 0; c < NCH; ++c) {
        size_t o = ((size_t)pair * NCH + c) * DSTATE + n;
        float a = cha[o];
        float b = chs[o];
        sst[o] = s;
        s = a * s + b;
    }
}

// ------------------------------------------------- scan pass C: final y + gate
// NOTE: yf aliases zbuf elementwise — same-lane read-then-write, safe.
__global__ void k_scan_final(const float* __restrict__ delta, const bf16* __restrict__ xcs,
                             const float* __restrict__ xdbl, const bf16* __restrict__ zbuf,
                             const float* __restrict__ A_log, const float* __restrict__ Dp,
                             const float* __restrict__ sst, bf16* __restrict__ yf) {
    int tid = threadIdx.x;
    int g = blockIdx.x * 16 + (tid >> 4);
    int n = tid & 15;
    int pair = g & (NPAIR - 1);
    int chunk = g >> 12;
    int b = pair >> 11;
    int d = pair & (D_INNER - 1);
    float A  = -expf(A_log[d * DSTATE + n]);
    float Dv = Dp[d];
    float s  = sst[((size_t)pair * NCH + chunk) * DSTATE + n];
    size_t tbase = (size_t)b * SEQ + chunk * CHLEN;
    for (int i = 0; i < CHLEN; ++i) {
        size_t t = tbase + i;
        float dl = delta[t * D_INNER + d];
        float u  = b2f(xcs[t * D_INNER + d]);
        float Bn = xdbl[t * XDS + 64 + n];
        float Cn = xdbl[t * XDS + 80 + n];
        float dA = expf(dl * A);
        s = dA * s + dl * Bn * u;
        float y = s * Cn;
        y += __shfl_xor(y, 1, 16);
        y += __shfl_xor(y, 2, 16);
        y += __shfl_xor(y, 4, 16);
        y += __shfl_xor(y, 8, 16);
        if (n == 0) {
            float zv = b2f(zbuf[t * D_INNER + d]);
            float sz = zv / (1.f + expf(-zv));
            yf[t * D_INNER + d] = f2b((y + u * Dv) * sz);
        }
    }
}

// ---------------------------------------------------------------- launch
extern "C" void kernel_launch(void* const* d_in, const int* in_sizes, int n_in,
                              void* d_out, int out_size, void* d_ws, size_t ws_size,
                              hipStream_t stream) {
    const float* x      = (const float*)d_in[0];
    const float* ln_g   = (const float*)d_in[1];
    const float* ln_b   = (const float*)d_in[2];
    const float* W_in   = (const float*)d_in[3];
    const float* conv_w = (const float*)d_in[4];
    const float* conv_b = (const float*)d_in[5];
    const float* A_log  = (const float*)d_in[6];
    const float* D_par  = (const float*)d_in[7];
    const float* xpw    = (const float*)d_in[8];
    const float* dtw    = (const float*)d_in[9];
    const float* dtb    = (const float*)d_in[10];
    const float* W_out  = (const float*)d_in[11];
    float* out = (float*)d_out;

    char* ws = (char*)d_ws;
    // workspace (~78.9 MB), stage-lifetime aliased:
    //  [0,        8388608)  xn bf16 (dead after GEMM1) -> cha 4MB@0, chs 4MB@4MB; sst=cha
    //  [8388608, 41943040)  xc fp32 (dead after conv)  -> delta fp32 -> wOutb bf16 (after scan_final)
    //  [41943040,58720256)  z bf16                     <- yf aliases z (elementwise-safe)
    //  [58720256,75497472)  wInb bf16 (dead after GEMM1) -> xcs bf16
    //  [75497472,77594624)  xdbl fp32 (4096x128)
    //  [77594624,78118912)  drb bf16 (4096x64)
    //  [78118912,78381056)  dtwb bf16 (2048x64)
    //  [78381056,78905344)  xpwb bf16 (128x2048, zero-padded rows 96..127)
    bf16*  xn    = (bf16*)(ws + 0);
    float* cha   = (float*)(ws + 0);
    float* chs   = (float*)(ws + 4194304);
    float* sst   = cha;
    float* xc    = (float*)(ws + 8388608);
    float* delta = xc;
    short* wOutb = (short*)(ws + 8388608);
    bf16*  z     = (bf16*)(ws + 41943040);
    bf16*  yf    = z;
    short* wInb  = (short*)(ws + 58720256);
    bf16*  xcs   = (bf16*)(ws + 58720256);
    float* xdbl  = (float*)(ws + 75497472);
    short* drb   = (short*)(ws + 77594624);
    short* dtwb  = (short*)(ws + 78118912);
    short* xpwb  = (short*)(ws + 78381056);

    k_layernorm<<<NTOK, 256, 0, stream>>>(x, ln_g, ln_b, xn);
    k_f2b<<<(2 * D_INNER * D_MODEL / 4) / 256, 256, 0, stream>>>(W_in, wInb);
    // in-proj GEMM: 4096 x 4096 x 1024
    k_gemm_mfma<<<dim3(2 * D_INNER / 128, NTOK / 128, 1), 256, 0, stream>>>(
        (const short*)xn, wInb, 2 * D_INNER, D_MODEL, 0, xc, z, nullptr, nullptr, nullptr);
    k_conv<<<(NTOK * D_INNER) / 256, 256, 0, stream>>>(xc, conv_w, conv_b, xcs);
    // xproj GEMM: 4096 x 128 x 2048, split-K=8 with atomic accumulate
    k_zero<<<(NTOK * XDS / 4) / 256, 256, 0, stream>>>(xdbl);
    k_prep_xpw<<<(128 * D_INNER / 4) / 256, 256, 0, stream>>>(xpw, xpwb);
    k_gemm_mfma<<<dim3(1, NTOK / 128, 8), 256, 0, stream>>>(
        (const short*)xcs, xpwb, XDS, D_INNER, 2, xdbl, nullptr, nullptr, nullptr, nullptr);
    // delta GEMM: 4096 x 2048 x 64, epilogue softplus(acc + dtb)
    k_extract_dr<<<(NTOK * DTRANK / 4) / 256, 256, 0, stream>>>(xdbl, drb);
    k_f2b<<<(D_INNER * DTRANK / 4) / 256, 256, 0, stream>>>(dtw, dtwb);
    k_gemm_mfma<<<dim3(D_INNER / 128, NTOK / 128, 1), 256, 0, stream>>>(
        drb, dtwb, D_INNER, DTRANK, 3, delta, nullptr, nullptr, nullptr, dtb);
    // selective scan (3-pass)
    k_scan_partial<<<(NPAIR * NCH) / 16, 256, 0, stream>>>(delta, xcs, xdbl, A_log, cha, chs);
    k_scan_combine<<<(NPAIR * DSTATE) / 256, 256, 0, stream>>>(cha, chs, sst);
    k_scan_final<<<(NPAIR * NCH) / 16, 256, 0, stream>>>(delta, xcs, xdbl, z, A_log, D_par, sst, yf);
    // out-proj GEMM: 4096 x 1024 x 2048 + residual
    k_f2b<<<(D_MODEL * D_INNER / 4) / 256, 256, 0, stream>>>(W_out, wOutb);
    k_gemm_mfma<<<dim3(D_MODEL / 128, NTOK / 128, 1), 256, 0, stream>>>(
        (const short*)yf, wOutb, D_MODEL, D_INNER, 1, nullptr, nullptr, x, out, nullptr);
}

// Round 6
// 452.907 us; speedup vs baseline: 3.9773x; 1.5079x over previous
//
#include <hip/hip_runtime.h>
#include <hip/hip_bf16.h>
#include <math.h>

typedef __hip_bfloat16 bf16;

#define D_MODEL 1024
#define D_INNER 2048
#define NTOK    4096   // B*L
#define SEQ     2048
#define BSZ     2
#define DSTATE  16
#define DTRANK  64
#define NCH     64
#define CHLEN   32     // SEQ / NCH
#define NPAIR   4096   // BSZ * D_INNER
#define XDS     128    // xdbl row stride (fp32), padded from 96

__device__ __forceinline__ float b2f(bf16 v) { return __bfloat162float(v); }
__device__ __forceinline__ bf16  f2b(float v) { return __float2bfloat16(v); }
__device__ __forceinline__ short f2bs(float v) {
    bf16 h = __float2bfloat16(v);
    short s; __builtin_memcpy(&s, &h, 2); return s;
}

typedef __attribute__((ext_vector_type(8))) short short8;
typedef __attribute__((ext_vector_type(4))) float f32x4;

__device__ __forceinline__ void async_copy16(const void* g, void* l) {
    __builtin_amdgcn_global_load_lds(
        (const __attribute__((address_space(1))) unsigned int*)g,
        (__attribute__((address_space(3))) unsigned int*)l,
        16, 0, 0);
}

// ---------------------------------------------------------------- LayerNorm
__global__ void k_layernorm(const float* __restrict__ x, const float* __restrict__ g,
                            const float* __restrict__ b, bf16* __restrict__ xn) {
    int t = blockIdx.x;
    int tid = threadIdx.x;
    const float* row = x + (size_t)t * D_MODEL;
    float v[4];
    float s = 0.f, q = 0.f;
#pragma unroll
    for (int i = 0; i < 4; ++i) {
        int idx = tid + i * 256;
        v[i] = row[idx];
        s += v[i]; q += v[i] * v[i];
    }
    __shared__ float sh_s[256], sh_q[256];
    sh_s[tid] = s; sh_q[tid] = q;
    __syncthreads();
    for (int o = 128; o > 0; o >>= 1) {
        if (tid < o) { sh_s[tid] += sh_s[tid + o]; sh_q[tid] += sh_q[tid + o]; }
        __syncthreads();
    }
    float mu  = sh_s[0] * (1.f / D_MODEL);
    float var = sh_q[0] * (1.f / D_MODEL) - mu * mu;
    float rs  = rsqrtf(var + 1e-5f);
#pragma unroll
    for (int i = 0; i < 4; ++i) {
        int idx = tid + i * 256;
        float o = (v[i] - mu) * rs * g[idx] + b[idx];
        xn[(size_t)t * D_MODEL + idx] = f2b(o);
    }
}

// ---------------------------------------------------------------- fp32 -> bf16 convert
__global__ void k_f2b(const float* __restrict__ in, short* __restrict__ out) {
    int i = blockIdx.x * 256 + threadIdx.x;
    float4 v = reinterpret_cast<const float4*>(in)[i];
    short4 o;
    o.x = f2bs(v.x); o.y = f2bs(v.y); o.z = f2bs(v.z); o.w = f2bs(v.w);
    reinterpret_cast<short4*>(out)[i] = o;
}

// ---------------------------------------------------------------- zero fp32 buffer
__global__ void k_zero(float* __restrict__ p) {
    int i = blockIdx.x * 256 + threadIdx.x;
    reinterpret_cast<float4*>(p)[i] = (float4){0.f, 0.f, 0.f, 0.f};
}

// --------------------------------------------- xpw (96x2048 fp32) -> padded 128x2048 bf16
__global__ void k_prep_xpw(const float* __restrict__ in, short* __restrict__ out) {
    int i = blockIdx.x * 256 + threadIdx.x;
    int row = i >> 9;
    short4 o;
    if (row < 96) {
        float4 v = reinterpret_cast<const float4*>(in)[i];
        o.x = f2bs(v.x); o.y = f2bs(v.y); o.z = f2bs(v.z); o.w = f2bs(v.w);
    } else {
        o.x = o.y = o.z = o.w = 0;
    }
    reinterpret_cast<short4*>(out)[i] = o;
}

// --------------------------------------------- dr = xdbl[:, 0:64] -> bf16 (4096x64)
__global__ void k_extract_dr(const float* __restrict__ xdbl, short* __restrict__ drb) {
    int i = blockIdx.x * 256 + threadIdx.x;
    int t = i >> 4;
    int jg = (i & 15) * 4;
    float4 v = *reinterpret_cast<const float4*>(&xdbl[(size_t)t * XDS + jg]);
    short4 o;
    o.x = f2bs(v.x); o.y = f2bs(v.y); o.z = f2bs(v.z); o.w = f2bs(v.w);
    *reinterpret_cast<short4*>(&drb[(size_t)t * DTRANK + jg]) = o;
}

// ---------------------------------------------------------------- MFMA GEMM (NT)
// mode 0: split at D_INNER -> Cf fp32 / Cz bf16   (in-proj)
// mode 1: Cout = acc + res (fp32, residual)       (out-proj)
// mode 2: atomicAdd(Cf, acc)                      (xproj, split-K via blockIdx.z)
// mode 3: Cf = softplus(acc + bias[col]) fp32     (delta)
#define GBK 32
__global__ __launch_bounds__(256) void k_gemm_mfma(
    const short* __restrict__ A, const short* __restrict__ Bw,
    int N, int K, int mode,
    float* __restrict__ Cf, bf16* __restrict__ Cz,
    const float* __restrict__ res, float* __restrict__ Cout,
    const float* __restrict__ bias)
{
    __shared__ short As[128 * GBK];
    __shared__ short Bs[128 * GBK];
    const int tid  = threadIdx.x;
    const int lane = tid & 63;
    const int wave = tid >> 6;
    const int wm = wave >> 1, wn = wave & 1;
    const int m0 = blockIdx.y * 128;
    const int n0 = blockIdx.x * 128;
    const int lm   = lane & 15;
    const int koff = (lane >> 4) * 8;

    const int srow = tid >> 2;
    const int skc  = (tid & 3) * 8;
    const size_t a_off0 = (size_t)(m0 + srow) * K + skc;
    const size_t a_off1 = (size_t)(m0 + srow + 64) * K + skc;
    const size_t b_off0 = (size_t)(n0 + srow) * K + skc;
    const size_t b_off1 = (size_t)(n0 + srow + 64) * K + skc;
    char* lA0 = (char*)As + tid * 16;
    char* lA1 = (char*)As + 4096 + tid * 16;
    char* lB0 = (char*)Bs + tid * 16;
    char* lB1 = (char*)Bs + 4096 + tid * 16;

    f32x4 acc[4][4];
#pragma unroll
    for (int i = 0; i < 4; ++i)
#pragma unroll
        for (int j = 0; j < 4; ++j)
            acc[i][j] = (f32x4){0.f, 0.f, 0.f, 0.f};

    const int kchunk = K / gridDim.z;
    const int kbeg = blockIdx.z * kchunk;
    const int kend = kbeg + kchunk;
    for (int k0 = kbeg; k0 < kend; k0 += GBK) {
        __syncthreads();
        async_copy16(A + a_off0 + k0, lA0);
        async_copy16(A + a_off1 + k0, lA1);
        async_copy16(Bw + b_off0 + k0, lB0);
        async_copy16(Bw + b_off1 + k0, lB1);
        __syncthreads();

        short8 af[4], bf[4];
#pragma unroll
        for (int t = 0; t < 4; ++t) {
            af[t] = *reinterpret_cast<const short8*>(&As[(wm * 64 + t * 16 + lm) * GBK + koff]);
            bf[t] = *reinterpret_cast<const short8*>(&Bs[(wn * 64 + t * 16 + lm) * GBK + koff]);
        }
#pragma unroll
        for (int tm = 0; tm < 4; ++tm)
#pragma unroll
            for (int tn = 0; tn < 4; ++tn)
                acc[tm][tn] = __builtin_amdgcn_mfma_f32_16x16x32_bf16(
                    af[tm], bf[tn], acc[tm][tn], 0, 0, 0);
    }

    const int rq = (lane >> 4) * 4;
#pragma unroll
    for (int tm = 0; tm < 4; ++tm) {
#pragma unroll
        for (int tn = 0; tn < 4; ++tn) {
            f32x4 v = acc[tm][tn];
            int col = n0 + wn * 64 + tn * 16 + lm;
#pragma unroll
            for (int r = 0; r < 4; ++r) {
                int row = m0 + wm * 64 + tm * 16 + rq + r;
                float val = v[r];
                if (mode == 0) {
                    if (col < D_INNER) Cf[(size_t)row * D_INNER + col] = val;
                    else               Cz[(size_t)row * D_INNER + (col - D_INNER)] = f2b(val);
                } else if (mode == 1) {
                    Cout[(size_t)row * N + col] = val + res[(size_t)row * N + col];
                } else if (mode == 2) {
                    atomicAdd(&Cf[(size_t)row * N + col], val);
                } else {
                    float a = val + bias[col];
                    float sp = (a > 20.f) ? a : log1pf(expf(a));
                    Cf[(size_t)row * N + col] = sp;
                }
            }
        }
    }
}

// ------------------------------------------------- causal depthwise conv + SiLU
__global__ void k_conv(const float* __restrict__ xc, const float* __restrict__ cw,
                       const float* __restrict__ cb, bf16* __restrict__ xcs) {
    size_t idx = (size_t)blockIdx.x * blockDim.x + threadIdx.x;
    int d = (int)(idx & (D_INNER - 1));
    int l = (int)((idx >> 11) & (SEQ - 1));
    float w0 = cw[d * 4 + 0], w1 = cw[d * 4 + 1];
    float w2 = cw[d * 4 + 2], w3 = cw[d * 4 + 3];
    const float* base = xc + idx;
    float acc = cb[d] + w3 * base[0];
    if (l >= 1) acc += w2 * base[-(int)D_INNER];
    if (l >= 2) acc += w1 * base[-2 * (int)D_INNER];
    if (l >= 3) acc += w0 * base[-3 * (int)D_INNER];
    xcs[idx] = f2b(acc / (1.f + __expf(-acc)));   // silu
}

// ------------------------------------------------- scan pass A: per-chunk partials
// one thread per (b, chunk, d): 16 states in registers, B row staged in LDS.
// grid (D_INNER/256, NCH, BSZ), block 256.
__global__ __launch_bounds__(256) void k_scan_partialB(
    const float* __restrict__ delta, const bf16* __restrict__ xcs,
    const float* __restrict__ xdbl, const float* __restrict__ A_log,
    bf16* __restrict__ chs, float* __restrict__ sumdl)
{
    __shared__ float Bsh[CHLEN][16];
    const int tid = threadIdx.x;
    const int d = blockIdx.x * 256 + tid;
    const int chunk = blockIdx.y;
    const int b = blockIdx.z;
    const size_t tbase = (size_t)b * SEQ + (size_t)chunk * CHLEN;

    // stage B[t][0:16] for the chunk (32x16 floats); threads 0..127
    if (tid < 128) {
        int t = tid >> 2, j = (tid & 3) * 4;
        float4 v = *reinterpret_cast<const float4*>(&xdbl[(tbase + t) * XDS + 64 + j]);
        *reinterpret_cast<float4*>(&Bsh[t][j]) = v;
    }
    float An[16];
#pragma unroll
    for (int j = 0; j < 4; ++j) {
        float4 v = *reinterpret_cast<const float4*>(&A_log[(size_t)d * DSTATE + j * 4]);
        An[j * 4 + 0] = -__expf(v.x); An[j * 4 + 1] = -__expf(v.y);
        An[j * 4 + 2] = -__expf(v.z); An[j * 4 + 3] = -__expf(v.w);
    }
    __syncthreads();

    float s[16];
#pragma unroll
    for (int n = 0; n < 16; ++n) s[n] = 0.f;
    float sd = 0.f;
    for (int t = 0; t < CHLEN; ++t) {
        size_t gt = tbase + t;
        float dl = delta[gt * D_INNER + d];
        float u  = b2f(xcs[gt * D_INNER + d]);
        float dlu = dl * u;
        sd += dl;
#pragma unroll
        for (int n = 0; n < 16; ++n) {
            float dA = __expf(dl * An[n]);
            s[n] = fmaf(dA, s[n], dlu * Bsh[t][n]);
        }
    }
    const int pair = b * D_INNER + d;
    bf16* co = chs + ((size_t)pair * NCH + chunk) * DSTATE;
#pragma unroll
    for (int n = 0; n < 16; ++n) co[n] = f2b(s[n]);
    sumdl[(size_t)pair * NCH + chunk] = sd;
}

// ------------------------------------------------- scan pass B: chunk-prefix combine
// thread per (pair, n); aprod(chunk) = exp(A_n * sumdl(chunk)).
// sst ALIASES chs: read chunk-sum before writing entry state (same thread+element).
__global__ void k_scan_combineB(const bf16* __restrict__ chs, const float* __restrict__ sumdl,
                                const float* __restrict__ A_log, bf16* __restrict__ sst) {
    int idx = blockIdx.x * 256 + threadIdx.x;
    int pair = idx >> 4;
    int n = idx & 15;
    int d = pair & (D_INNER - 1);
    float An = -__expf(A_log[(size_t)d * DSTATE + n]);
    float s = 0.f;
    for (int c = 0; c < NCH; ++c) {
        size_t o = ((size_t)pair * NCH + c) * DSTATE + n;
        float loc = b2f(chs[o]);
        float ap = __expf(An * sumdl[(size_t)pair * NCH + c]);
        sst[o] = f2b(s);
        s = fmaf(ap, s, loc);
    }
}

// ------------------------------------------------- scan pass C: final y + gate
// one thread per (b, chunk, d); B,C staged in LDS; y in-register; no shuffles.
// yf aliases zbuf elementwise (same-thread read-then-write).
__global__ __launch_bounds__(256) void k_scan_finalB(
    const float* __restrict__ delta, const bf16* __restrict__ xcs,
    const float* __restrict__ xdbl, const bf16* __restrict__ zbuf,
    const float* __restrict__ A_log, const float* __restrict__ Dp,
    const bf16* __restrict__ sst, bf16* __restrict__ yf)
{
    __shared__ float BC[CHLEN][32];   // [t][0:16]=B, [t][16:32]=C
    const int tid = threadIdx.x;
    const int d = blockIdx.x * 256 + tid;
    const int chunk = blockIdx.y;
    const int b = blockIdx.z;
    const size_t tbase = (size_t)b * SEQ + (size_t)chunk * CHLEN;

    {
        int t = tid >> 3, j = (tid & 7) * 4;
        float4 v = *reinterpret_cast<const float4*>(&xdbl[(tbase + t) * XDS + 64 + j]);
        *reinterpret_cast<float4*>(&BC[t][j]) = v;
    }
    float An[16];
#pragma unroll
    for (int j = 0; j < 4; ++j) {
        float4 v = *reinterpret_cast<const float4*>(&A_log[(size_t)d * DSTATE + j * 4]);
        An[j * 4 + 0] = -__expf(v.x); An[j * 4 + 1] = -__expf(v.y);
        An[j * 4 + 2] = -__expf(v.z); An[j * 4 + 3] = -__expf(v.w);
    }
    const int pair = b * D_INNER + d;
    float s[16];
    const bf16* so = sst + ((size_t)pair * NCH + chunk) * DSTATE;
#pragma unroll
    for (int n = 0; n < 16; ++n) s[n] = b2f(so[n]);
    const float Dv = Dp[d];
    __syncthreads();

    for (int t = 0; t < CHLEN; ++t) {
        size_t gt = tbase + t;
        float dl = delta[gt * D_INNER + d];
        float u  = b2f(xcs[gt * D_INNER + d]);
        float dlu = dl * u;
        float y = 0.f;
#pragma unroll
        for (int n = 0; n < 16; ++n) {
            float dA = __expf(dl * An[n]);
            s[n] = fmaf(dA, s[n], dlu * BC[t][n]);
            y = fmaf(s[n], BC[t][16 + n], y);
        }
        float zv = b2f(zbuf[gt * D_INNER + d]);
        float sz = zv / (1.f + __expf(-zv));
        yf[gt * D_INNER + d] = f2b((y + u * Dv) * sz);
    }
}

// ---------------------------------------------------------------- launch
extern "C" void kernel_launch(void* const* d_in, const int* in_sizes, int n_in,
                              void* d_out, int out_size, void* d_ws, size_t ws_size,
                              hipStream_t stream) {
    const float* x      = (const float*)d_in[0];
    const float* ln_g   = (const float*)d_in[1];
    const float* ln_b   = (const float*)d_in[2];
    const float* W_in   = (const float*)d_in[3];
    const float* conv_w = (const float*)d_in[4];
    const float* conv_b = (const float*)d_in[5];
    const float* A_log  = (const float*)d_in[6];
    const float* D_par  = (const float*)d_in[7];
    const float* xpw    = (const float*)d_in[8];
    const float* dtw    = (const float*)d_in[9];
    const float* dtb    = (const float*)d_in[10];
    const float* W_out  = (const float*)d_in[11];
    float* out = (float*)d_out;

    char* ws = (char*)d_ws;
    // workspace (~76.3 MB), stage-lifetime aliased:
    //  [0,        8388608)  xn bf16 (dead after GEMM1) -> chs bf16 (4096x64x16), sst=chs
    //  [8388608, 41943040)  xc fp32 (dead after conv)  -> delta fp32 -> wOutb (after scan_final)
    //  [41943040,58720256)  z bf16                     <- yf aliases z
    //  [58720256,75497472)  wInb bf16 (dead after GEMM1) -> xcs bf16
    //  [75497472,77594624)  xdbl fp32 (4096x128)
    //  [77594624,78643200)  sumdl fp32 (4096x64)
    //  [78643200,79167488)  drb bf16 (4096x64)
    //  [79167488,79429632)  dtwb bf16 (2048x64)
    //  [79429632,79953920)  xpwb bf16 (128x2048)
    bf16*  xn    = (bf16*)(ws + 0);
    bf16*  chs   = (bf16*)(ws + 0);
    bf16*  sst   = chs;
    float* xc    = (float*)(ws + 8388608);
    float* delta = xc;
    short* wOutb = (short*)(ws + 8388608);
    bf16*  z     = (bf16*)(ws + 41943040);
    bf16*  yf    = z;
    short* wInb  = (short*)(ws + 58720256);
    bf16*  xcs   = (bf16*)(ws + 58720256);
    float* xdbl  = (float*)(ws + 75497472);
    float* sumdl = (float*)(ws + 77594624);
    short* drb   = (short*)(ws + 78643200);
    short* dtwb  = (short*)(ws + 79167488);
    short* xpwb  = (short*)(ws + 79429632);

    k_layernorm<<<NTOK, 256, 0, stream>>>(x, ln_g, ln_b, xn);
    k_f2b<<<(2 * D_INNER * D_MODEL / 4) / 256, 256, 0, stream>>>(W_in, wInb);
    // in-proj GEMM: 4096 x 4096 x 1024
    k_gemm_mfma<<<dim3(2 * D_INNER / 128, NTOK / 128, 1), 256, 0, stream>>>(
        (const short*)xn, wInb, 2 * D_INNER, D_MODEL, 0, xc, z, nullptr, nullptr, nullptr);
    k_conv<<<(NTOK * D_INNER) / 256, 256, 0, stream>>>(xc, conv_w, conv_b, xcs);
    // xproj GEMM: 4096 x 128 x 2048, split-K=8 atomic
    k_zero<<<(NTOK * XDS / 4) / 256, 256, 0, stream>>>(xdbl);
    k_prep_xpw<<<(128 * D_INNER / 4) / 256, 256, 0, stream>>>(xpw, xpwb);
    k_gemm_mfma<<<dim3(1, NTOK / 128, 8), 256, 0, stream>>>(
        (const short*)xcs, xpwb, XDS, D_INNER, 2, xdbl, nullptr, nullptr, nullptr, nullptr);
    // delta GEMM: 4096 x 2048 x 64, softplus epilogue
    k_extract_dr<<<(NTOK * DTRANK / 4) / 256, 256, 0, stream>>>(xdbl, drb);
    k_f2b<<<(D_INNER * DTRANK / 4) / 256, 256, 0, stream>>>(dtw, dtwb);
    k_gemm_mfma<<<dim3(D_INNER / 128, NTOK / 128, 1), 256, 0, stream>>>(
        drb, dtwb, D_INNER, DTRANK, 3, delta, nullptr, nullptr, nullptr, dtb);
    // selective scan (3-pass, register-state formulation)
    k_scan_partialB<<<dim3(D_INNER / 256, NCH, BSZ), 256, 0, stream>>>(
        delta, xcs, xdbl, A_log, chs, sumdl);
    k_scan_combineB<<<(NPAIR * DSTATE) / 256, 256, 0, stream>>>(chs, sumdl, A_log, sst);
    k_scan_finalB<<<dim3(D_INNER / 256, NCH, BSZ), 256, 0, stream>>>(
        delta, xcs, xdbl, z, A_log, D_par, sst, yf);
    // out-proj GEMM: 4096 x 1024 x 2048 + residual
    k_f2b<<<(D_MODEL * D_INNER / 4) / 256, 256, 0, stream>>>(W_out, wOutb);
    k_gemm_mfma<<<dim3(D_MODEL / 128, NTOK / 128, 1), 256, 0, stream>>>(
        (const short*)yf, wOutb, D_MODEL, D_INNER, 1, nullptr, nullptr, x, out, nullptr);
}

// Round 7
// 446.751 us; speedup vs baseline: 4.0321x; 1.0138x over previous
//
#include <hip/hip_runtime.h>
#include <hip/hip_bf16.h>
#include <math.h>

typedef __hip_bfloat16 bf16;

#define D_MODEL 1024
#define D_INNER 2048
#define NTOK    4096   // B*L
#define SEQ     2048
#define BSZ     2
#define DSTATE  16
#define DTRANK  64
#define NCH     64
#define CHLEN   32     // SEQ / NCH
#define NPAIR   4096   // BSZ * D_INNER
#define XDS     128    // xdbl row stride (fp32), padded from 96

__device__ __forceinline__ float b2f(bf16 v) { return __bfloat162float(v); }
__device__ __forceinline__ bf16  f2b(float v) { return __float2bfloat16(v); }
__device__ __forceinline__ short f2bs(float v) {
    bf16 h = __float2bfloat16(v);
    short s; __builtin_memcpy(&s, &h, 2); return s;
}

typedef __attribute__((ext_vector_type(8))) short short8;
typedef __attribute__((ext_vector_type(4))) float f32x4;

__device__ __forceinline__ void async_copy16(const void* g, void* l) {
    __builtin_amdgcn_global_load_lds(
        (const __attribute__((address_space(1))) unsigned int*)g,
        (__attribute__((address_space(3))) unsigned int*)l,
        16, 0, 0);
}

// ---------------------------------------------------------------- LayerNorm
__global__ void k_layernorm(const float* __restrict__ x, const float* __restrict__ g,
                            const float* __restrict__ b, bf16* __restrict__ xn) {
    int t = blockIdx.x;
    int tid = threadIdx.x;
    const float* row = x + (size_t)t * D_MODEL;
    float v[4];
    float s = 0.f, q = 0.f;
#pragma unroll
    for (int i = 0; i < 4; ++i) {
        int idx = tid + i * 256;
        v[i] = row[idx];
        s += v[i]; q += v[i] * v[i];
    }
    __shared__ float sh_s[256], sh_q[256];
    sh_s[tid] = s; sh_q[tid] = q;
    __syncthreads();
    for (int o = 128; o > 0; o >>= 1) {
        if (tid < o) { sh_s[tid] += sh_s[tid + o]; sh_q[tid] += sh_q[tid + o]; }
        __syncthreads();
    }
    float mu  = sh_s[0] * (1.f / D_MODEL);
    float var = sh_q[0] * (1.f / D_MODEL) - mu * mu;
    float rs  = rsqrtf(var + 1e-5f);
#pragma unroll
    for (int i = 0; i < 4; ++i) {
        int idx = tid + i * 256;
        float o = (v[i] - mu) * rs * g[idx] + b[idx];
        xn[(size_t)t * D_MODEL + idx] = f2b(o);
    }
}

// ---------------------------------------------------------------- fp32 -> bf16 convert
__global__ void k_f2b(const float* __restrict__ in, short* __restrict__ out) {
    int i = blockIdx.x * 256 + threadIdx.x;
    float4 v = reinterpret_cast<const float4*>(in)[i];
    short4 o;
    o.x = f2bs(v.x); o.y = f2bs(v.y); o.z = f2bs(v.z); o.w = f2bs(v.w);
    reinterpret_cast<short4*>(out)[i] = o;
}

// ---------------------------------------------------------------- zero fp32 buffer
__global__ void k_zero(float* __restrict__ p) {
    int i = blockIdx.x * 256 + threadIdx.x;
    reinterpret_cast<float4*>(p)[i] = (float4){0.f, 0.f, 0.f, 0.f};
}

// --------------------------------------------- xpw (96x2048 fp32) -> padded 128x2048 bf16
__global__ void k_prep_xpw(const float* __restrict__ in, short* __restrict__ out) {
    int i = blockIdx.x * 256 + threadIdx.x;
    int row = i >> 9;
    short4 o;
    if (row < 96) {
        float4 v = reinterpret_cast<const float4*>(in)[i];
        o.x = f2bs(v.x); o.y = f2bs(v.y); o.z = f2bs(v.z); o.w = f2bs(v.w);
    } else {
        o.x = o.y = o.z = o.w = 0;
    }
    reinterpret_cast<short4*>(out)[i] = o;
}

// --------------------------------------------- dr = xdbl[:, 0:64] -> bf16 (4096x64)
__global__ void k_extract_dr(const float* __restrict__ xdbl, short* __restrict__ drb) {
    int i = blockIdx.x * 256 + threadIdx.x;
    int t = i >> 4;
    int jg = (i & 15) * 4;
    float4 v = *reinterpret_cast<const float4*>(&xdbl[(size_t)t * XDS + jg]);
    short4 o;
    o.x = f2bs(v.x); o.y = f2bs(v.y); o.z = f2bs(v.z); o.w = f2bs(v.w);
    *reinterpret_cast<short4*>(&drb[(size_t)t * DTRANK + jg]) = o;
}

// ---------------------------------------------------------------- MFMA GEMM (NT)
// mode 0: split at D_INNER -> Cf fp32 / Cz bf16   (in-proj)
// mode 1: Cout = acc + res (fp32, residual)       (out-proj)
// mode 2: atomicAdd(Cf, acc)                      (xproj, split-K via blockIdx.z)
// mode 3: Cf = softplus(acc + bias[col]) fp32     (delta)
//
// LDS bank-conflict swizzle: global 16B chunk kc of row r is stored at LDS
// slot kc ^ ((r>>1)&3). Staging permutes the SOURCE address (global_load_lds
// lane->LDS mapping is fixed); fragment reads XOR their k-offset. Every
// 8-lane phase of ds_read_b128 then covers all 8 bank groups (conflict-free).
#define GBK 32
__global__ __launch_bounds__(256) void k_gemm_mfma(
    const short* __restrict__ A, const short* __restrict__ Bw,
    int N, int K, int mode,
    float* __restrict__ Cf, bf16* __restrict__ Cz,
    const float* __restrict__ res, float* __restrict__ Cout,
    const float* __restrict__ bias)
{
    __shared__ short As[128 * GBK];
    __shared__ short Bs[128 * GBK];
    const int tid  = threadIdx.x;
    const int lane = tid & 63;
    const int wave = tid >> 6;
    const int wm = wave >> 1, wn = wave & 1;
    const int m0 = blockIdx.y * 128;
    const int n0 = blockIdx.x * 128;
    const int lm   = lane & 15;
    // swizzled per-lane k-offset: logical chunk (lane>>4) ^ row-swizzle ((lane>>1)&3)
    const int koff = (((lane >> 4) ^ ((lane >> 1) & 3)) * 8);

    const int srow = tid >> 2;
    const int skc  = (((tid & 3) ^ ((tid >> 3) & 3)) * 8);   // swizzled source chunk
    const size_t a_off0 = (size_t)(m0 + srow) * K + skc;
    const size_t a_off1 = (size_t)(m0 + srow + 64) * K + skc;
    const size_t b_off0 = (size_t)(n0 + srow) * K + skc;
    const size_t b_off1 = (size_t)(n0 + srow + 64) * K + skc;
    char* lA0 = (char*)As + tid * 16;
    char* lA1 = (char*)As + 4096 + tid * 16;
    char* lB0 = (char*)Bs + tid * 16;
    char* lB1 = (char*)Bs + 4096 + tid * 16;

    f32x4 acc[4][4];
#pragma unroll
    for (int i = 0; i < 4; ++i)
#pragma unroll
        for (int j = 0; j < 4; ++j)
            acc[i][j] = (f32x4){0.f, 0.f, 0.f, 0.f};

    const int kchunk = K / gridDim.z;
    const int kbeg = blockIdx.z * kchunk;
    const int kend = kbeg + kchunk;
    for (int k0 = kbeg; k0 < kend; k0 += GBK) {
        __syncthreads();
        async_copy16(A + a_off0 + k0, lA0);
        async_copy16(A + a_off1 + k0, lA1);
        async_copy16(Bw + b_off0 + k0, lB0);
        async_copy16(Bw + b_off1 + k0, lB1);
        __syncthreads();

        short8 af[4], bf[4];
#pragma unroll
        for (int t = 0; t < 4; ++t) {
            af[t] = *reinterpret_cast<const short8*>(&As[(wm * 64 + t * 16 + lm) * GBK + koff]);
            bf[t] = *reinterpret_cast<const short8*>(&Bs[(wn * 64 + t * 16 + lm) * GBK + koff]);
        }
#pragma unroll
        for (int tm = 0; tm < 4; ++tm)
#pragma unroll
            for (int tn = 0; tn < 4; ++tn)
                acc[tm][tn] = __builtin_amdgcn_mfma_f32_16x16x32_bf16(
                    af[tm], bf[tn], acc[tm][tn], 0, 0, 0);
    }

    const int rq = (lane >> 4) * 4;
#pragma unroll
    for (int tm = 0; tm < 4; ++tm) {
#pragma unroll
        for (int tn = 0; tn < 4; ++tn) {
            f32x4 v = acc[tm][tn];
            int col = n0 + wn * 64 + tn * 16 + lm;
#pragma unroll
            for (int r = 0; r < 4; ++r) {
                int row = m0 + wm * 64 + tm * 16 + rq + r;
                float val = v[r];
                if (mode == 0) {
                    if (col < D_INNER) Cf[(size_t)row * D_INNER + col] = val;
                    else               Cz[(size_t)row * D_INNER + (col - D_INNER)] = f2b(val);
                } else if (mode == 1) {
                    Cout[(size_t)row * N + col] = val + res[(size_t)row * N + col];
                } else if (mode == 2) {
                    atomicAdd(&Cf[(size_t)row * N + col], val);
                } else {
                    float a = val + bias[col];
                    float sp = (a > 20.f) ? a : log1pf(expf(a));
                    Cf[(size_t)row * N + col] = sp;
                }
            }
        }
    }
}

// ------------------------------------------------- causal depthwise conv + SiLU
__global__ void k_conv(const float* __restrict__ xc, const float* __restrict__ cw,
                       const float* __restrict__ cb, bf16* __restrict__ xcs) {
    size_t idx = (size_t)blockIdx.x * blockDim.x + threadIdx.x;
    int d = (int)(idx & (D_INNER - 1));
    int l = (int)((idx >> 11) & (SEQ - 1));
    float w0 = cw[d * 4 + 0], w1 = cw[d * 4 + 1];
    float w2 = cw[d * 4 + 2], w3 = cw[d * 4 + 3];
    const float* base = xc + idx;
    float acc = cb[d] + w3 * base[0];
    if (l >= 1) acc += w2 * base[-(int)D_INNER];
    if (l >= 2) acc += w1 * base[-2 * (int)D_INNER];
    if (l >= 3) acc += w0 * base[-3 * (int)D_INNER];
    xcs[idx] = f2b(acc / (1.f + __expf(-acc)));   // silu
}

// ------------------------------------------------- scan pass A: per-chunk partials
__global__ __launch_bounds__(256) void k_scan_partialB(
    const float* __restrict__ delta, const bf16* __restrict__ xcs,
    const float* __restrict__ xdbl, const float* __restrict__ A_log,
    bf16* __restrict__ chs, float* __restrict__ sumdl)
{
    __shared__ float Bsh[CHLEN][16];
    const int tid = threadIdx.x;
    const int d = blockIdx.x * 256 + tid;
    const int chunk = blockIdx.y;
    const int b = blockIdx.z;
    const size_t tbase = (size_t)b * SEQ + (size_t)chunk * CHLEN;

    if (tid < 128) {
        int t = tid >> 2, j = (tid & 3) * 4;
        float4 v = *reinterpret_cast<const float4*>(&xdbl[(tbase + t) * XDS + 64 + j]);
        *reinterpret_cast<float4*>(&Bsh[t][j]) = v;
    }
    float An[16];
#pragma unroll
    for (int j = 0; j < 4; ++j) {
        float4 v = *reinterpret_cast<const float4*>(&A_log[(size_t)d * DSTATE + j * 4]);
        An[j * 4 + 0] = -__expf(v.x); An[j * 4 + 1] = -__expf(v.y);
        An[j * 4 + 2] = -__expf(v.z); An[j * 4 + 3] = -__expf(v.w);
    }
    __syncthreads();

    float s[16];
#pragma unroll
    for (int n = 0; n < 16; ++n) s[n] = 0.f;
    float sd = 0.f;
    for (int t = 0; t < CHLEN; ++t) {
        size_t gt = tbase + t;
        float dl = delta[gt * D_INNER + d];
        float u  = b2f(xcs[gt * D_INNER + d]);
        float dlu = dl * u;
        sd += dl;
#pragma unroll
        for (int n = 0; n < 16; ++n) {
            float dA = __expf(dl * An[n]);
            s[n] = fmaf(dA, s[n], dlu * Bsh[t][n]);
        }
    }
    const int pair = b * D_INNER + d;
    bf16* co = chs + ((size_t)pair * NCH + chunk) * DSTATE;
#pragma unroll
    for (int n = 0; n < 16; ++n) co[n] = f2b(s[n]);
    sumdl[(size_t)pair * NCH + chunk] = sd;
}

// ------------------------------------------------- scan pass B: chunk-prefix combine
// sst ALIASES chs: read chunk-sum before writing entry state (same thread+element).
__global__ void k_scan_combineB(const bf16* __restrict__ chs, const float* __restrict__ sumdl,
                                const float* __restrict__ A_log, bf16* __restrict__ sst) {
    int idx = blockIdx.x * 256 + threadIdx.x;
    int pair = idx >> 4;
    int n = idx & 15;
    int d = pair & (D_INNER - 1);
    float An = -__expf(A_log[(size_t)d * DSTATE + n]);
    float s = 0.f;
    for (int c = 0; c < NCH; ++c) {
        size_t o = ((size_t)pair * NCH + c) * DSTATE + n;
        float loc = b2f(chs[o]);
        float ap = __expf(An * sumdl[(size_t)pair * NCH + c]);
        sst[o] = f2b(s);
        s = fmaf(ap, s, loc);
    }
}

// ------------------------------------------------- scan pass C: final y + gate
// yf aliases zbuf elementwise (same-thread read-then-write).
__global__ __launch_bounds__(256) void k_scan_finalB(
    const float* __restrict__ delta, const bf16* __restrict__ xcs,
    const float* __restrict__ xdbl, const bf16* __restrict__ zbuf,
    const float* __restrict__ A_log, const float* __restrict__ Dp,
    const bf16* __restrict__ sst, bf16* __restrict__ yf)
{
    __shared__ float BC[CHLEN][32];   // [t][0:16]=B, [t][16:32]=C
    const int tid = threadIdx.x;
    const int d = blockIdx.x * 256 + tid;
    const int chunk = blockIdx.y;
    const int b = blockIdx.z;
    const size_t tbase = (size_t)b * SEQ + (size_t)chunk * CHLEN;

    {
        int t = tid >> 3, j = (tid & 7) * 4;
        float4 v = *reinterpret_cast<const float4*>(&xdbl[(tbase + t) * XDS + 64 + j]);
        *reinterpret_cast<float4*>(&BC[t][j]) = v;
    }
    float An[16];
#pragma unroll
    for (int j = 0; j < 4; ++j) {
        float4 v = *reinterpret_cast<const float4*>(&A_log[(size_t)d * DSTATE + j * 4]);
        An[j * 4 + 0] = -__expf(v.x); An[j * 4 + 1] = -__expf(v.y);
        An[j * 4 + 2] = -__expf(v.z); An[j * 4 + 3] = -__expf(v.w);
    }
    const int pair = b * D_INNER + d;
    float s[16];
    const bf16* so = sst + ((size_t)pair * NCH + chunk) * DSTATE;
#pragma unroll
    for (int n = 0; n < 16; ++n) s[n] = b2f(so[n]);
    const float Dv = Dp[d];
    __syncthreads();

    for (int t = 0; t < CHLEN; ++t) {
        size_t gt = tbase + t;
        float dl = delta[gt * D_INNER + d];
        float u  = b2f(xcs[gt * D_INNER + d]);
        float dlu = dl * u;
        float y = 0.f;
#pragma unroll
        for (int n = 0; n < 16; ++n) {
            float dA = __expf(dl * An[n]);
            s[n] = fmaf(dA, s[n], dlu * BC[t][n]);
            y = fmaf(s[n], BC[t][16 + n], y);
        }
        float zv = b2f(zbuf[gt * D_INNER + d]);
        float sz = zv / (1.f + __expf(-zv));
        yf[gt * D_INNER + d] = f2b((y + u * Dv) * sz);
    }
}

// ---------------------------------------------------------------- launch
extern "C" void kernel_launch(void* const* d_in, const int* in_sizes, int n_in,
                              void* d_out, int out_size, void* d_ws, size_t ws_size,
                              hipStream_t stream) {
    const float* x      = (const float*)d_in[0];
    const float* ln_g   = (const float*)d_in[1];
    const float* ln_b   = (const float*)d_in[2];
    const float* W_in   = (const float*)d_in[3];
    const float* conv_w = (const float*)d_in[4];
    const float* conv_b = (const float*)d_in[5];
    const float* A_log  = (const float*)d_in[6];
    const float* D_par  = (const float*)d_in[7];
    const float* xpw    = (const float*)d_in[8];
    const float* dtw    = (const float*)d_in[9];
    const float* dtb    = (const float*)d_in[10];
    const float* W_out  = (const float*)d_in[11];
    float* out = (float*)d_out;

    char* ws = (char*)d_ws;
    // workspace (~76.3 MB), stage-lifetime aliased (unchanged from R5):
    bf16*  xn    = (bf16*)(ws + 0);
    bf16*  chs   = (bf16*)(ws + 0);
    bf16*  sst   = chs;
    float* xc    = (float*)(ws + 8388608);
    float* delta = xc;
    short* wOutb = (short*)(ws + 8388608);
    bf16*  z     = (bf16*)(ws + 41943040);
    bf16*  yf    = z;
    short* wInb  = (short*)(ws + 58720256);
    bf16*  xcs   = (bf16*)(ws + 58720256);
    float* xdbl  = (float*)(ws + 75497472);
    float* sumdl = (float*)(ws + 77594624);
    short* drb   = (short*)(ws + 78643200);
    short* dtwb  = (short*)(ws + 79167488);
    short* xpwb  = (short*)(ws + 79429632);

    k_layernorm<<<NTOK, 256, 0, stream>>>(x, ln_g, ln_b, xn);
    k_f2b<<<(2 * D_INNER * D_MODEL / 4) / 256, 256, 0, stream>>>(W_in, wInb);
    // in-proj GEMM: 4096 x 4096 x 1024
    k_gemm_mfma<<<dim3(2 * D_INNER / 128, NTOK / 128, 1), 256, 0, stream>>>(
        (const short*)xn, wInb, 2 * D_INNER, D_MODEL, 0, xc, z, nullptr, nullptr, nullptr);
    k_conv<<<(NTOK * D_INNER) / 256, 256, 0, stream>>>(xc, conv_w, conv_b, xcs);
    // xproj GEMM: 4096 x 128 x 2048, split-K=8 atomic
    k_zero<<<(NTOK * XDS / 4) / 256, 256, 0, stream>>>(xdbl);
    k_prep_xpw<<<(128 * D_INNER / 4) / 256, 256, 0, stream>>>(xpw, xpwb);
    k_gemm_mfma<<<dim3(1, NTOK / 128, 8), 256, 0, stream>>>(
        (const short*)xcs, xpwb, XDS, D_INNER, 2, xdbl, nullptr, nullptr, nullptr, nullptr);
    // delta GEMM: 4096 x 2048 x 64, softplus epilogue
    k_extract_dr<<<(NTOK * DTRANK / 4) / 256, 256, 0, stream>>>(xdbl, drb);
    k_f2b<<<(D_INNER * DTRANK / 4) / 256, 256, 0, stream>>>(dtw, dtwb);
    k_gemm_mfma<<<dim3(D_INNER / 128, NTOK / 128, 1), 256, 0, stream>>>(
        drb, dtwb, D_INNER, DTRANK, 3, delta, nullptr, nullptr, nullptr, dtb);
    // selective scan (3-pass, register-state formulation)
    k_scan_partialB<<<dim3(D_INNER / 256, NCH, BSZ), 256, 0, stream>>>(
        delta, xcs, xdbl, A_log, chs, sumdl);
    k_scan_combineB<<<(NPAIR * DSTATE) / 256, 256, 0, stream>>>(chs, sumdl, A_log, sst);
    k_scan_finalB<<<dim3(D_INNER / 256, NCH, BSZ), 256, 0, stream>>>(
        delta, xcs, xdbl, z, A_log, D_par, sst, yf);
    // out-proj GEMM: 4096 x 1024 x 2048 + residual
    k_f2b<<<(D_MODEL * D_INNER / 4) / 256, 256, 0, stream>>>(W_out, wOutb);
    k_gemm_mfma<<<dim3(D_MODEL / 128, NTOK / 128, 1), 256, 0, stream>>>(
        (const short*)yf, wOutb, D_MODEL, D_INNER, 1, nullptr, nullptr, x, out, nullptr);
}

// Round 8
// 433.029 us; speedup vs baseline: 4.1599x; 1.0317x over previous
//
#include <hip/hip_runtime.h>
#include <hip/hip_bf16.h>
#include <math.h>

typedef __hip_bfloat16 bf16;

#define D_MODEL 1024
#define D_INNER 2048
#define NTOK    4096   // B*L
#define SEQ     2048
#define BSZ     2
#define DSTATE  16
#define DTRANK  64
#define NCH     64
#define CHLEN   32     // SEQ / NCH
#define NPAIR   4096   // BSZ * D_INNER
#define XDS     128    // xdbl row stride (fp32), padded from 96

__device__ __forceinline__ float b2f(bf16 v) { return __bfloat162float(v); }
__device__ __forceinline__ bf16  f2b(float v) { return __float2bfloat16(v); }
__device__ __forceinline__ short f2bs(float v) {
    bf16 h = __float2bfloat16(v);
    short s; __builtin_memcpy(&s, &h, 2); return s;
}

typedef __attribute__((ext_vector_type(8))) short short8;
typedef __attribute__((ext_vector_type(4))) float f32x4;

__device__ __forceinline__ void async_copy16(const void* g, void* l) {
    __builtin_amdgcn_global_load_lds(
        (const __attribute__((address_space(1))) unsigned int*)g,
        (__attribute__((address_space(3))) unsigned int*)l,
        16, 0, 0);
}

// ---------------------------------------------------------------- LayerNorm
__global__ void k_layernorm(const float* __restrict__ x, const float* __restrict__ g,
                            const float* __restrict__ b, bf16* __restrict__ xn) {
    int t = blockIdx.x;
    int tid = threadIdx.x;
    const float* row = x + (size_t)t * D_MODEL;
    float v[4];
    float s = 0.f, q = 0.f;
#pragma unroll
    for (int i = 0; i < 4; ++i) {
        int idx = tid + i * 256;
        v[i] = row[idx];
        s += v[i]; q += v[i] * v[i];
    }
    __shared__ float sh_s[256], sh_q[256];
    sh_s[tid] = s; sh_q[tid] = q;
    __syncthreads();
    for (int o = 128; o > 0; o >>= 1) {
        if (tid < o) { sh_s[tid] += sh_s[tid + o]; sh_q[tid] += sh_q[tid + o]; }
        __syncthreads();
    }
    float mu  = sh_s[0] * (1.f / D_MODEL);
    float var = sh_q[0] * (1.f / D_MODEL) - mu * mu;
    float rs  = rsqrtf(var + 1e-5f);
#pragma unroll
    for (int i = 0; i < 4; ++i) {
        int idx = tid + i * 256;
        float o = (v[i] - mu) * rs * g[idx] + b[idx];
        xn[(size_t)t * D_MODEL + idx] = f2b(o);
    }
}

// ---------------------------------------------------------------- fp32 -> bf16 convert
__global__ void k_f2b(const float* __restrict__ in, short* __restrict__ out) {
    int i = blockIdx.x * 256 + threadIdx.x;
    float4 v = reinterpret_cast<const float4*>(in)[i];
    short4 o;
    o.x = f2bs(v.x); o.y = f2bs(v.y); o.z = f2bs(v.z); o.w = f2bs(v.w);
    reinterpret_cast<short4*>(out)[i] = o;
}

// ---------------------------------------------------------------- zero fp32 buffer
__global__ void k_zero(float* __restrict__ p) {
    int i = blockIdx.x * 256 + threadIdx.x;
    reinterpret_cast<float4*>(p)[i] = (float4){0.f, 0.f, 0.f, 0.f};
}

// --------------------------------------------- xpw (96x2048 fp32) -> padded 128x2048 bf16
__global__ void k_prep_xpw(const float* __restrict__ in, short* __restrict__ out) {
    int i = blockIdx.x * 256 + threadIdx.x;
    int row = i >> 9;
    short4 o;
    if (row < 96) {
        float4 v = reinterpret_cast<const float4*>(in)[i];
        o.x = f2bs(v.x); o.y = f2bs(v.y); o.z = f2bs(v.z); o.w = f2bs(v.w);
    } else {
        o.x = o.y = o.z = o.w = 0;
    }
    reinterpret_cast<short4*>(out)[i] = o;
}

// --------------------------------------------- dr = xdbl[:, 0:64] -> bf16 (4096x64)
__global__ void k_extract_dr(const float* __restrict__ xdbl, short* __restrict__ drb) {
    int i = blockIdx.x * 256 + threadIdx.x;
    int t = i >> 4;
    int jg = (i & 15) * 4;
    float4 v = *reinterpret_cast<const float4*>(&xdbl[(size_t)t * XDS + jg]);
    short4 o;
    o.x = f2bs(v.x); o.y = f2bs(v.y); o.z = f2bs(v.z); o.w = f2bs(v.w);
    *reinterpret_cast<short4*>(&drb[(size_t)t * DTRANK + jg]) = o;
}

// ---------------------------------------------------------------- MFMA GEMM (NT)
// mode 0: split at D_INNER -> Cf fp32 / Cz bf16   (in-proj)
// mode 1: Cout = acc + res (fp32, residual)       (out-proj)
// mode 2: atomicAdd(Cf, acc)                      (xproj, split-K via blockIdx.z)
// mode 3: Cf = softplus(acc + bias[col]) fp32     (delta)
//
// Double-buffered LDS + single barrier per K-iter: loads for iter i+1 are
// issued AFTER the barrier and overlap compute of iter i; the vmcnt(0) drain
// at iter i+1's barrier lands after ~compute-length of overlap. Buffer reuse
// distance = 2 iters, so one barrier/iter also protects overwrite.
// LDS bank-conflict XOR swizzle (R7, verified conflict-free) retained.
#define GBK 32
#define BUFE (128 * GBK)   // elements per buffer per matrix
__global__ __launch_bounds__(256) void k_gemm_mfma(
    const short* __restrict__ A, const short* __restrict__ Bw,
    int N, int K, int mode,
    float* __restrict__ Cf, bf16* __restrict__ Cz,
    const float* __restrict__ res, float* __restrict__ Cout,
    const float* __restrict__ bias)
{
    __shared__ short As[2 * BUFE];
    __shared__ short Bs[2 * BUFE];
    const int tid  = threadIdx.x;
    const int lane = tid & 63;
    const int wave = tid >> 6;
    const int wm = wave >> 1, wn = wave & 1;
    const int m0 = blockIdx.y * 128;
    const int n0 = blockIdx.x * 128;
    const int lm   = lane & 15;
    const int koff = (((lane >> 4) ^ ((lane >> 1) & 3)) * 8);

    const int srow = tid >> 2;
    const int skc  = (((tid & 3) ^ ((tid >> 3) & 3)) * 8);   // swizzled source chunk
    const size_t a_off0 = (size_t)(m0 + srow) * K + skc;
    const size_t a_off1 = (size_t)(m0 + srow + 64) * K + skc;
    const size_t b_off0 = (size_t)(n0 + srow) * K + skc;
    const size_t b_off1 = (size_t)(n0 + srow + 64) * K + skc;
    char* lA0 = (char*)As + tid * 16;
    char* lB0 = (char*)Bs + tid * 16;

    f32x4 acc[4][4];
#pragma unroll
    for (int i = 0; i < 4; ++i)
#pragma unroll
        for (int j = 0; j < 4; ++j)
            acc[i][j] = (f32x4){0.f, 0.f, 0.f, 0.f};

    const int kchunk = K / gridDim.z;
    const int kbeg = blockIdx.z * kchunk;
    const int kend = kbeg + kchunk;

    // prologue: stage first tile into buffer 0
    async_copy16(A + a_off0 + kbeg, lA0);
    async_copy16(A + a_off1 + kbeg, lA0 + 4096);
    async_copy16(Bw + b_off0 + kbeg, lB0);
    async_copy16(Bw + b_off1 + kbeg, lB0 + 4096);

    int cur = 0;
    for (int k0 = kbeg; k0 < kend; k0 += GBK) {
        __syncthreads();   // drains vmcnt: buf[cur] ready; prior compute on buf[cur^1] done
        int k1 = k0 + GBK;
        if (k1 < kend) {
            int nxt = cur ^ 1;
            async_copy16(A + a_off0 + k1, lA0 + nxt * (BUFE * 2));
            async_copy16(A + a_off1 + k1, lA0 + nxt * (BUFE * 2) + 4096);
            async_copy16(Bw + b_off0 + k1, lB0 + nxt * (BUFE * 2));
            async_copy16(Bw + b_off1 + k1, lB0 + nxt * (BUFE * 2) + 4096);
        }

        const short* Ab = As + cur * BUFE;
        const short* Bb = Bs + cur * BUFE;
        short8 af[4], bf[4];
#pragma unroll
        for (int t = 0; t < 4; ++t) {
            af[t] = *reinterpret_cast<const short8*>(&Ab[(wm * 64 + t * 16 + lm) * GBK + koff]);
            bf[t] = *reinterpret_cast<const short8*>(&Bb[(wn * 64 + t * 16 + lm) * GBK + koff]);
        }
#pragma unroll
        for (int tm = 0; tm < 4; ++tm)
#pragma unroll
            for (int tn = 0; tn < 4; ++tn)
                acc[tm][tn] = __builtin_amdgcn_mfma_f32_16x16x32_bf16(
                    af[tm], bf[tn], acc[tm][tn], 0, 0, 0);
        cur ^= 1;
    }

    const int rq = (lane >> 4) * 4;
#pragma unroll
    for (int tm = 0; tm < 4; ++tm) {
#pragma unroll
        for (int tn = 0; tn < 4; ++tn) {
            f32x4 v = acc[tm][tn];
            int col = n0 + wn * 64 + tn * 16 + lm;
#pragma unroll
            for (int r = 0; r < 4; ++r) {
                int row = m0 + wm * 64 + tm * 16 + rq + r;
                float val = v[r];
                if (mode == 0) {
                    if (col < D_INNER) Cf[(size_t)row * D_INNER + col] = val;
                    else               Cz[(size_t)row * D_INNER + (col - D_INNER)] = f2b(val);
                } else if (mode == 1) {
                    Cout[(size_t)row * N + col] = val + res[(size_t)row * N + col];
                } else if (mode == 2) {
                    atomicAdd(&Cf[(size_t)row * N + col], val);
                } else {
                    float a = val + bias[col];
                    float sp = (a > 20.f) ? a : log1pf(expf(a));
                    Cf[(size_t)row * N + col] = sp;
                }
            }
        }
    }
}

// ------------------------------------------------- causal depthwise conv + SiLU
__global__ void k_conv(const float* __restrict__ xc, const float* __restrict__ cw,
                       const float* __restrict__ cb, bf16* __restrict__ xcs) {
    size_t idx = (size_t)blockIdx.x * blockDim.x + threadIdx.x;
    int d = (int)(idx & (D_INNER - 1));
    int l = (int)((idx >> 11) & (SEQ - 1));
    float w0 = cw[d * 4 + 0], w1 = cw[d * 4 + 1];
    float w2 = cw[d * 4 + 2], w3 = cw[d * 4 + 3];
    const float* base = xc + idx;
    float acc = cb[d] + w3 * base[0];
    if (l >= 1) acc += w2 * base[-(int)D_INNER];
    if (l >= 2) acc += w1 * base[-2 * (int)D_INNER];
    if (l >= 3) acc += w0 * base[-3 * (int)D_INNER];
    xcs[idx] = f2b(acc / (1.f + __expf(-acc)));   // silu
}

// ------------------------------------------------- scan pass A: per-chunk partials
__global__ __launch_bounds__(256) void k_scan_partialB(
    const float* __restrict__ delta, const bf16* __restrict__ xcs,
    const float* __restrict__ xdbl, const float* __restrict__ A_log,
    bf16* __restrict__ chs, float* __restrict__ sumdl)
{
    __shared__ float Bsh[CHLEN][16];
    const int tid = threadIdx.x;
    const int d = blockIdx.x * 256 + tid;
    const int chunk = blockIdx.y;
    const int b = blockIdx.z;
    const size_t tbase = (size_t)b * SEQ + (size_t)chunk * CHLEN;

    if (tid < 128) {
        int t = tid >> 2, j = (tid & 3) * 4;
        float4 v = *reinterpret_cast<const float4*>(&xdbl[(tbase + t) * XDS + 64 + j]);
        *reinterpret_cast<float4*>(&Bsh[t][j]) = v;
    }
    float An[16];
#pragma unroll
    for (int j = 0; j < 4; ++j) {
        float4 v = *reinterpret_cast<const float4*>(&A_log[(size_t)d * DSTATE + j * 4]);
        An[j * 4 + 0] = -__expf(v.x); An[j * 4 + 1] = -__expf(v.y);
        An[j * 4 + 2] = -__expf(v.z); An[j * 4 + 3] = -__expf(v.w);
    }
    __syncthreads();

    float s[16];
#pragma unroll
    for (int n = 0; n < 16; ++n) s[n] = 0.f;
    float sd = 0.f;
    for (int t = 0; t < CHLEN; ++t) {
        size_t gt = tbase + t;
        float dl = delta[gt * D_INNER + d];
        float u  = b2f(xcs[gt * D_INNER + d]);
        float dlu = dl * u;
        sd += dl;
#pragma unroll
        for (int n = 0; n < 16; ++n) {
            float dA = __expf(dl * An[n]);
            s[n] = fmaf(dA, s[n], dlu * Bsh[t][n]);
        }
    }
    const int pair = b * D_INNER + d;
    bf16* co = chs + ((size_t)pair * NCH + chunk) * DSTATE;
#pragma unroll
    for (int n = 0; n < 16; ++n) co[n] = f2b(s[n]);
    sumdl[(size_t)pair * NCH + chunk] = sd;
}

// ------------------------------------------------- scan pass B: chunk-prefix combine
// sst ALIASES chs: read chunk-sum before writing entry state (same thread+element).
__global__ void k_scan_combineB(const bf16* __restrict__ chs, const float* __restrict__ sumdl,
                                const float* __restrict__ A_log, bf16* __restrict__ sst) {
    int idx = blockIdx.x * 256 + threadIdx.x;
    int pair = idx >> 4;
    int n = idx & 15;
    int d = pair & (D_INNER - 1);
    float An = -__expf(A_log[(size_t)d * DSTATE + n]);
    float s = 0.f;
    for (int c = 0; c < NCH; ++c) {
        size_t o = ((size_t)pair * NCH + c) * DSTATE + n;
        float loc = b2f(chs[o]);
        float ap = __expf(An * sumdl[(size_t)pair * NCH + c]);
        sst[o] = f2b(s);
        s = fmaf(ap, s, loc);
    }
}

// ------------------------------------------------- scan pass C: final y + gate
// yf aliases zbuf elementwise (same-thread read-then-write).
__global__ __launch_bounds__(256) void k_scan_finalB(
    const float* __restrict__ delta, const bf16* __restrict__ xcs,
    const float* __restrict__ xdbl, const bf16* __restrict__ zbuf,
    const float* __restrict__ A_log, const float* __restrict__ Dp,
    const bf16* __restrict__ sst, bf16* __restrict__ yf)
{
    __shared__ float BC[CHLEN][32];   // [t][0:16]=B, [t][16:32]=C
    const int tid = threadIdx.x;
    const int d = blockIdx.x * 256 + tid;
    const int chunk = blockIdx.y;
    const int b = blockIdx.z;
    const size_t tbase = (size_t)b * SEQ + (size_t)chunk * CHLEN;

    {
        int t = tid >> 3, j = (tid & 7) * 4;
        float4 v = *reinterpret_cast<const float4*>(&xdbl[(tbase + t) * XDS + 64 + j]);
        *reinterpret_cast<float4*>(&BC[t][j]) = v;
    }
    float An[16];
#pragma unroll
    for (int j = 0; j < 4; ++j) {
        float4 v = *reinterpret_cast<const float4*>(&A_log[(size_t)d * DSTATE + j * 4]);
        An[j * 4 + 0] = -__expf(v.x); An[j * 4 + 1] = -__expf(v.y);
        An[j * 4 + 2] = -__expf(v.z); An[j * 4 + 3] = -__expf(v.w);
    }
    const int pair = b * D_INNER + d;
    float s[16];
    const bf16* so = sst + ((size_t)pair * NCH + chunk) * DSTATE;
#pragma unroll
    for (int n = 0; n < 16; ++n) s[n] = b2f(so[n]);
    const float Dv = Dp[d];
    __syncthreads();

    for (int t = 0; t < CHLEN; ++t) {
        size_t gt = tbase + t;
        float dl = delta[gt * D_INNER + d];
        float u  = b2f(xcs[gt * D_INNER + d]);
        float dlu = dl * u;
        float y = 0.f;
#pragma unroll
        for (int n = 0; n < 16; ++n) {
            float dA = __expf(dl * An[n]);
            s[n] = fmaf(dA, s[n], dlu * BC[t][n]);
            y = fmaf(s[n], BC[t][16 + n], y);
        }
        float zv = b2f(zbuf[gt * D_INNER + d]);
        float sz = zv / (1.f + __expf(-zv));
        yf[gt * D_INNER + d] = f2b((y + u * Dv) * sz);
    }
}

// ---------------------------------------------------------------- launch
extern "C" void kernel_launch(void* const* d_in, const int* in_sizes, int n_in,
                              void* d_out, int out_size, void* d_ws, size_t ws_size,
                              hipStream_t stream) {
    const float* x      = (const float*)d_in[0];
    const float* ln_g   = (const float*)d_in[1];
    const float* ln_b   = (const float*)d_in[2];
    const float* W_in   = (const float*)d_in[3];
    const float* conv_w = (const float*)d_in[4];
    const float* conv_b = (const float*)d_in[5];
    const float* A_log  = (const float*)d_in[6];
    const float* D_par  = (const float*)d_in[7];
    const float* xpw    = (const float*)d_in[8];
    const float* dtw    = (const float*)d_in[9];
    const float* dtb    = (const float*)d_in[10];
    const float* W_out  = (const float*)d_in[11];
    float* out = (float*)d_out;

    char* ws = (char*)d_ws;
    // workspace (~79.9 MB), stage-lifetime aliased (unchanged from R5):
    bf16*  xn    = (bf16*)(ws + 0);
    bf16*  chs   = (bf16*)(ws + 0);
    bf16*  sst   = chs;
    float* xc    = (float*)(ws + 8388608);
    float* delta = xc;
    short* wOutb = (short*)(ws + 8388608);
    bf16*  z     = (bf16*)(ws + 41943040);
    bf16*  yf    = z;
    short* wInb  = (short*)(ws + 58720256);
    bf16*  xcs   = (bf16*)(ws + 58720256);
    float* xdbl  = (float*)(ws + 75497472);
    float* sumdl = (float*)(ws + 77594624);
    short* drb   = (short*)(ws + 78643200);
    short* dtwb  = (short*)(ws + 79167488);
    short* xpwb  = (short*)(ws + 79429632);

    k_layernorm<<<NTOK, 256, 0, stream>>>(x, ln_g, ln_b, xn);
    k_f2b<<<(2 * D_INNER * D_MODEL / 4) / 256, 256, 0, stream>>>(W_in, wInb);
    // in-proj GEMM: 4096 x 4096 x 1024
    k_gemm_mfma<<<dim3(2 * D_INNER / 128, NTOK / 128, 1), 256, 0, stream>>>(
        (const short*)xn, wInb, 2 * D_INNER, D_MODEL, 0, xc, z, nullptr, nullptr, nullptr);
    k_conv<<<(NTOK * D_INNER) / 256, 256, 0, stream>>>(xc, conv_w, conv_b, xcs);
    // xproj GEMM: 4096 x 128 x 2048, split-K=8 atomic
    k_zero<<<(NTOK * XDS / 4) / 256, 256, 0, stream>>>(xdbl);
    k_prep_xpw<<<(128 * D_INNER / 4) / 256, 256, 0, stream>>>(xpw, xpwb);
    k_gemm_mfma<<<dim3(1, NTOK / 128, 8), 256, 0, stream>>>(
        (const short*)xcs, xpwb, XDS, D_INNER, 2, xdbl, nullptr, nullptr, nullptr, nullptr);
    // delta GEMM: 4096 x 2048 x 64, softplus epilogue
    k_extract_dr<<<(NTOK * DTRANK / 4) / 256, 256, 0, stream>>>(xdbl, drb);
    k_f2b<<<(D_INNER * DTRANK / 4) / 256, 256, 0, stream>>>(dtw, dtwb);
    k_gemm_mfma<<<dim3(D_INNER / 128, NTOK / 128, 1), 256, 0, stream>>>(
        drb, dtwb, D_INNER, DTRANK, 3, delta, nullptr, nullptr, nullptr, dtb);
    // selective scan (3-pass, register-state formulation)
    k_scan_partialB<<<dim3(D_INNER / 256, NCH, BSZ), 256, 0, stream>>>(
        delta, xcs, xdbl, A_log, chs, sumdl);
    k_scan_combineB<<<(NPAIR * DSTATE) / 256, 256, 0, stream>>>(chs, sumdl, A_log, sst);
    k_scan_finalB<<<dim3(D_INNER / 256, NCH, BSZ), 256, 0, stream>>>(
        delta, xcs, xdbl, z, A_log, D_par, sst, yf);
    // out-proj GEMM: 4096 x 1024 x 2048 + residual
    k_f2b<<<(D_MODEL * D_INNER / 4) / 256, 256, 0, stream>>>(W_out, wOutb);
    k_gemm_mfma<<<dim3(D_MODEL / 128, NTOK / 128, 1), 256, 0, stream>>>(
        (const short*)yf, wOutb, D_MODEL, D_INNER, 1, nullptr, nullptr, x, out, nullptr);
}